// Round 1
// baseline (4539.883 us; speedup 1.0000x reference)
//
#include <hip/hip_runtime.h>
#include <math.h>

#define MINN 1e-15f
#define MAXN 0.996f  // (1 - 4e-3)/sqrt(c), c=1

__device__ __forceinline__ float artanhf_(float v){
  v = fminf(fmaxf(v, -0.9999999f), 0.9999999f);
  return 0.5f*(log1pf(v) - log1pf(-v));
}
__device__ __forceinline__ float grp8(float v){
  v += __shfl_xor(v,1,8); v += __shfl_xor(v,2,8); v += __shfl_xor(v,4,8); return v;
}
__device__ __forceinline__ float grp16(float v){
  v += __shfl_xor(v,1,16); v += __shfl_xor(v,2,16);
  v += __shfl_xor(v,4,16); v += __shfl_xor(v,8,16); return v;
}

// --- transpose+pad w1 -> w1t[k][tx*4+j] = w1[tx+32j][k], k<1440, zero-padded ---
__global__ __launch_bounds__(256) void k_prep_w1t(const float* __restrict__ w1, float* __restrict__ w1t){
  int idx = blockIdx.x*256 + threadIdx.x;        // < 1440*128
  int k = idx >> 7, p = idx & 127;
  int tx = p >> 2, j = p & 3;
  int col = tx + 32*j;
  float v = (k < 1433 && col < 100) ? w1[(size_t)col*1433 + k] : 0.f;
  w1t[idx] = v;
}

// --- hyperbolic biases: hb = proj(expmap0(b)), plus ||hb||^2 ---
__global__ void k_bias(const float* __restrict__ b1, const float* __restrict__ b2,
                       float* __restrict__ hb1, float* __restrict__ hb2, float* __restrict__ scal){
  __shared__ float red[128];
  int t = threadIdx.x;
  float v = (t < 100) ? b1[t] : 0.f;
  red[t] = v*v; __syncthreads();
  for (int s=64;s;s>>=1){ if (t<s) red[t]+=red[t+s]; __syncthreads(); }
  float n2 = red[0]; __syncthreads();
  float n = fmaxf(sqrtf(n2), MINN);
  float s1 = tanhf(n)/n;
  float pn = fmaxf(tanhf(n), MINN);
  float t1 = pn > MAXN ? MAXN/pn : 1.f;
  float hv = s1*t1*v;
  hb1[t] = (t<100) ? hv : 0.f;
  red[t] = (t<100) ? hv*hv : 0.f; __syncthreads();
  for (int s=64;s;s>>=1){ if (t<s) red[t]+=red[t+s]; __syncthreads(); }
  if (t==0) scal[0] = red[0];
  __syncthreads();
  float v2 = (t < 64) ? b2[t] : 0.f;
  red[t] = v2*v2; __syncthreads();
  for (int s=64;s;s>>=1){ if (t<s) red[t]+=red[t+s]; __syncthreads(); }
  float n2b = red[0]; __syncthreads();
  float nb = fmaxf(sqrtf(n2b), MINN);
  float s1b = tanhf(nb)/nb;
  float pnb = fmaxf(tanhf(nb), MINN);
  float t1b = pnb > MAXN ? MAXN/pnb : 1.f;
  float hvb = s1b*t1b*v2;
  if (t < 64) hb2[t] = hvb;
  red[t] = (t<64) ? hvb*hvb : 0.f; __syncthreads();
  for (int s=64;s;s>>=1){ if (t<s) red[t]+=red[t+s]; __syncthreads(); }
  if (t==0) scal[1] = red[0];
}

// --- fused: encode(expmap0+proj) -> mobius_matvec(w1) -> proj -> mobius_add(hb1) -> proj -> logmap0
// GEMM: 32 rows x 128 cols (100 used) per block, K=1433, plus row sumsq of x fused in.
__global__ __launch_bounds__(256) void k_lin1(
    const float* __restrict__ x, const float* __restrict__ w1t,
    const float* __restrict__ hb1, const float* __restrict__ scal,
    float* __restrict__ xtan1, int N)
{
  __shared__ alignas(16) float xsT[16][36];   // [k][row], stride 36 keeps 16B align
  __shared__ alignas(16) float ws[16][128];   // [k][tx*4+j]
  __shared__ float ys[32][132];
  __shared__ float xn2s[32];
  __shared__ float hbs[128];
  int tid = threadIdx.x;
  int tx = tid & 31, ty = tid >> 5;           // rows 4*ty..4*ty+3, cols tx+32j
  int bm = blockIdx.x * 32;
  if (tid < 128) hbs[tid] = hb1[tid];
  float b1sq = scal[0];
  float acc[4][4] = {};
  float xsq0 = 0.f, xsq1 = 0.f;
  int r0 = tid >> 4, k0i = tid & 15;
  for (int k0 = 0; k0 < 1433; k0 += 16) {
    int gk = k0 + k0i;
    bool kv = gk < 1433;
    int gr0 = bm + r0, gr1 = gr0 + 16;
    float v0 = (kv && gr0 < N) ? x[(size_t)gr0*1433 + gk] : 0.f;
    float v1 = (kv && gr1 < N) ? x[(size_t)gr1*1433 + gk] : 0.f;
    xsT[k0i][r0] = v0; xsT[k0i][r0+16] = v1;
    xsq0 += v0*v0; xsq1 += v1*v1;
    const float4* w4 = reinterpret_cast<const float4*>(w1t + (size_t)k0*128);
    float4* s4 = reinterpret_cast<float4*>(&ws[0][0]);
    s4[tid] = w4[tid];
    s4[tid+256] = w4[tid+256];
    __syncthreads();
    #pragma unroll
    for (int k = 0; k < 16; ++k) {
      float4 av = *reinterpret_cast<const float4*>(&xsT[k][ty*4]);
      float4 bv = *reinterpret_cast<const float4*>(&ws[k][tx*4]);
      float a[4] = {av.x, av.y, av.z, av.w};
      float b[4] = {bv.x, bv.y, bv.z, bv.w};
      #pragma unroll
      for (int i=0;i<4;i++)
        #pragma unroll
        for (int j=0;j<4;j++) acc[i][j] += a[i]*b[j];
    }
    __syncthreads();
  }
  xsq0 = grp16(xsq0); xsq1 = grp16(xsq1);
  if ((tid & 15) == 0) { xn2s[r0] = xsq0; xn2s[r0+16] = xsq1; }
  #pragma unroll
  for (int i=0;i<4;i++)
    #pragma unroll
    for (int j=0;j<4;j++)
      ys[4*ty + i][tx + 32*j] = acc[i][j];
  __syncthreads();

  int rr = tid >> 3, g = tid & 7;
  int grow = bm + rr;
  float yn2 = 0.f, dotb = 0.f;
  for (int c = g; c < 100; c += 8) { float v = ys[rr][c]; yn2 += v*v; dotb += v*hbs[c]; }
  yn2 = grp8(yn2); dotb = grp8(dotb);
  float un = fmaxf(sqrtf(xn2s[rr]), MINN);
  float th = tanhf(un);
  float sE = th/un;                         // expmap0 scale
  float pn = fmaxf(th, MINN);
  float t1 = pn > MAXN ? MAXN/pn : 1.f;     // proj
  float gam = sE*t1;                        // h = gam*x
  float xh = fmaxf(gam*un, MINN);           // ||h||
  float yn = sqrtf(yn2);
  float mxn = fmaxf(gam*yn, MINN);          // ||mx||
  float rs = tanhf(mxn/xh*artanhf_(xh))/mxn;
  if (yn2 == 0.f) rs = 0.f;                 // all(mx==0) guard
  float rn = rs*gam*yn;                     // ||res||
  float t2 = rn > MAXN ? MAXN/fmaxf(rn,MINN) : 1.f;
  float alpha = t2*rs*gam;                  // mv = alpha*y
  float x2 = alpha*alpha*yn2;
  float xy = alpha*dotb;
  float den = fmaxf(1.f + 2.f*xy + x2*b1sq, MINN);
  float A = (1.f + 2.f*xy + b1sq)/den, B = (1.f - x2)/den;
  float Aa = A*alpha;
  float on2 = 0.f;
  for (int c=g;c<100;c+=8){ float o = Aa*ys[rr][c] + B*hbs[c]; on2 += o*o; }
  on2 = grp8(on2);
  float on = sqrtf(on2);
  float onc = fmaxf(on, MINN);
  float t3 = onc > MAXN ? MAXN/onc : 1.f;
  float pn3 = fmaxf(t3*on, MINN);
  float fs = artanhf_(pn3)/pn3 * t3;        // logmap0 scale * proj
  if (grow < N)
    for (int c=g;c<100;c+=8){ float o = Aa*ys[rr][c] + B*hbs[c]; xtan1[(size_t)grow*100 + c] = fs*o; }
}

// --- edge scatter: sup[row] += w * xt[col], DCH float4-chunks of DD floats ---
template<int DCH, int DD>
__global__ __launch_bounds__(256) void k_agg(const float* __restrict__ xt, const int* __restrict__ er,
    const int* __restrict__ ec, const float* __restrict__ ew, float* __restrict__ sup, int E)
{
  int gid = blockIdx.x*256 + threadIdx.x;
  if (gid >= E*DCH) return;
  int e = gid/DCH, q = gid - e*DCH;
  int rr = er[e], cc = ec[e];
  float wt = ew[e];
  const float4 v = *reinterpret_cast<const float4*>(xt + (size_t)cc*DD + q*4);
  float* dst = sup + (size_t)rr*DD + q*4;
  unsafeAtomicAdd(dst+0, wt*v.x);
  unsafeAtomicAdd(dst+1, wt*v.y);
  unsafeAtomicAdd(dst+2, wt*v.z);
  unsafeAtomicAdd(dst+3, wt*v.w);
}

// --- fused: proj(expmap0(support1)) -> hyp_act -> mobius_matvec(w2) -> +bias2 -> proj -> logmap0 ---
__global__ __launch_bounds__(256) void k_layer2(
    const float* __restrict__ sup, const float* __restrict__ w2,
    const float* __restrict__ hb2, const float* __restrict__ scal,
    float* __restrict__ xtan2, int N)
{
  __shared__ alignas(16) float w2s[64][100];
  __shared__ float xts[32][105];
  __shared__ float hbs[64];
  int tid = threadIdx.x;
  for (int i = tid; i < 1600; i += 256)
    reinterpret_cast<float4*>(&w2s[0][0])[i] = reinterpret_cast<const float4*>(w2)[i];
  if (tid < 64) hbs[tid] = hb2[tid];
  float b2sq = scal[1];
  __syncthreads();
  int rr = tid >> 3, g = tid & 7;
  int grow = blockIdx.x*32 + rr;
  bool valid = grow < N;
  float sv[13]; float sn2 = 0.f;
  #pragma unroll
  for (int m=0;m<13;m++){
    int j = g + 8*m;
    float v = (valid && j < 100) ? sup[(size_t)grow*100 + j] : 0.f;
    sv[m] = v; sn2 += v*v;
  }
  sn2 = grp8(sn2);
  float snn = fmaxf(sqrtf(sn2), MINN);
  float e1 = tanhf(snn)/snn;
  float pnA = fmaxf(tanhf(snn), MINN);
  float t1 = pnA > MAXN ? MAXN/pnA : 1.f;
  float phi = e1*t1;                          // h_agg = phi*s
  float hn = fmaxf(phi*snn, MINN);
  float lam = artanhf_(hn)/hn;                // logmap0
  float xn2 = 0.f;
  #pragma unroll
  for (int m=0;m<13;m++){
    int j = g + 8*m;
    if (j < 100){ float v = fmaxf(lam*phi*sv[m], 0.f); xts[rr][j] = v; xn2 += v*v; }
  }
  xn2 = grp8(xn2);
  float xn = fmaxf(sqrtf(xn2), MINN);
  float e2 = tanhf(xn)/xn;
  float pnB = fmaxf(tanhf(xn), MINN);
  float t2 = pnB > MAXN ? MAXN/pnB : 1.f;
  float psi = e2*t2;                          // h2in = psi*xt
  __syncthreads();
  float z[8] = {};
  for (int j=0;j<100;j++){
    float xv = xts[rr][j];
    #pragma unroll
    for (int m=0;m<8;m++) z[m] += xv * w2s[g+8*m][j];
  }
  float zn2 = 0.f, dz = 0.f;
  #pragma unroll
  for (int m=0;m<8;m++){ zn2 += z[m]*z[m]; dz += z[m]*hbs[g+8*m]; }
  zn2 = grp8(zn2); dz = grp8(dz);
  float xnh = fmaxf(psi*xn, MINN);
  float zn = sqrtf(zn2);
  float mxn = fmaxf(psi*zn, MINN);
  float rs = tanhf(mxn/xnh*artanhf_(xnh))/mxn;
  if (zn2 == 0.f) rs = 0.f;
  float rn = rs*psi*zn;
  float t3 = rn > MAXN ? MAXN/fmaxf(rn,MINN) : 1.f;
  float alpha = t3*rs*psi;                    // mv = alpha*z
  float x2 = alpha*alpha*zn2;
  float xy = alpha*dz;
  float den = fmaxf(1.f + 2.f*xy + x2*b2sq, MINN);
  float A = (1.f + 2.f*xy + b2sq)/den, B = (1.f - x2)/den;
  float Aa = A*alpha;
  float ov[8]; float on2 = 0.f;
  #pragma unroll
  for (int m=0;m<8;m++){ ov[m] = Aa*z[m] + B*hbs[g+8*m]; on2 += ov[m]*ov[m]; }
  on2 = grp8(on2);
  float on = sqrtf(on2);
  float onc = fmaxf(on, MINN);
  float t4 = onc > MAXN ? MAXN/onc : 1.f;
  float pn4 = fmaxf(t4*on, MINN);
  float fs = artanhf_(pn4)/pn4 * t4;
  if (valid)
    #pragma unroll
    for (int m=0;m<8;m++) xtan2[(size_t)grow*64 + g + 8*m] = fs*ov[m];
}

// --- fused: proj(expmap0(support2)) -> hyp_act -> logmap0 -> linear(7) + relu -> log_softmax ---
__global__ __launch_bounds__(256) void k_decode(
    const float* __restrict__ sup2, const float* __restrict__ lw,
    const float* __restrict__ lb, float* __restrict__ out, int N)
{
  __shared__ float lws[7][64];
  __shared__ float lbs[7];
  int tid = threadIdx.x;
  for (int i = tid; i < 448; i += 256) lws[i>>6][i&63] = lw[i];
  if (tid < 7) lbs[tid] = lb[tid];
  __syncthreads();
  int rr = tid >> 3, g = tid & 7;
  int grow = blockIdx.x*32 + rr;
  bool valid = grow < N;
  float sv[8]; float sn2 = 0.f;
  #pragma unroll
  for (int m=0;m<8;m++){
    int j = g + 8*m;
    float v = valid ? sup2[(size_t)grow*64 + j] : 0.f;
    sv[m] = v; sn2 += v*v;
  }
  sn2 = grp8(sn2);
  float snn = fmaxf(sqrtf(sn2), MINN);
  float e1 = tanhf(snn)/snn;
  float pnA = fmaxf(tanhf(snn), MINN);
  float t1 = pnA > MAXN ? MAXN/pnA : 1.f;
  float phi = e1*t1;
  float hn = fmaxf(phi*snn, MINN);
  float lam = artanhf_(hn)/hn;
  float xt[8]; float xn2 = 0.f;
  #pragma unroll
  for (int m=0;m<8;m++){ xt[m] = fmaxf(lam*phi*sv[m], 0.f); xn2 += xt[m]*xt[m]; }
  xn2 = grp8(xn2);
  float xn = fmaxf(sqrtf(xn2), MINN);
  float e2 = tanhf(xn)/xn;
  float pnB = fmaxf(tanhf(xn), MINN);
  float t2 = pnB > MAXN ? MAXN/pnB : 1.f;
  float psi = e2*t2;
  float tn = fmaxf(psi*xn, MINN);
  float lam2 = artanhf_(tn)/tn;
  float tc = lam2*psi;
  float lg[7];
  #pragma unroll
  for (int k=0;k<7;k++){
    float p = 0.f;
    #pragma unroll
    for (int m=0;m<8;m++) p += xt[m]*lws[k][g+8*m];
    p = grp8(p) * tc;
    lg[k] = fmaxf(p + lbs[k], 0.f);
  }
  float mx = lg[0];
  #pragma unroll
  for (int k=1;k<7;k++) mx = fmaxf(mx, lg[k]);
  float se = 0.f;
  #pragma unroll
  for (int k=0;k<7;k++) se += expf(lg[k]-mx);
  float lse = logf(se);
  if (valid && g < 7) out[(size_t)grow*7 + g] = lg[g] - mx - lse;
}

extern "C" void kernel_launch(void* const* d_in, const int* in_sizes, int n_in,
                              void* d_out, int out_size, void* d_ws, size_t ws_size,
                              hipStream_t stream)
{
  const float* x  = (const float*)d_in[0];
  const int*   er = (const int*)  d_in[1];
  const int*   ec = (const int*)  d_in[2];
  const float* ew = (const float*)d_in[3];
  const float* w1 = (const float*)d_in[4];
  const float* b1 = (const float*)d_in[5];
  const float* w2 = (const float*)d_in[6];
  const float* b2 = (const float*)d_in[7];
  const float* lw = (const float*)d_in[8];
  const float* lb = (const float*)d_in[9];
  float* out = (float*)d_out;
  int N = in_sizes[0] / 1433;
  int E = in_sizes[1];

  float* W    = (float*)d_ws;
  float* w1t  = W;                      // 1440*128 = 184320 floats
  float* hb1  = W + 184320;             // 128
  float* hb2  = W + 184448;             // 64
  float* scal = W + 184512;             // 2
  float* reg1 = W + 200000;             // N*100: xtan1, later xtan2
  float* reg2 = reg1 + (size_t)N*100;   // N*100: support1, later support2

  k_prep_w1t<<<720, 256, 0, stream>>>(w1, w1t);
  k_bias<<<1, 128, 0, stream>>>(b1, b2, hb1, hb2, scal);
  int nb32 = (N + 31)/32;
  k_lin1<<<nb32, 256, 0, stream>>>(x, w1t, hb1, scal, reg1, N);
  hipMemsetAsync(reg2, 0, (size_t)N*100*sizeof(float), stream);
  int g1 = (int)(((long long)E*25 + 255)/256);
  k_agg<25,100><<<g1, 256, 0, stream>>>(reg1, er, ec, ew, reg2, E);
  k_layer2<<<nb32, 256, 0, stream>>>(reg2, w2, hb2, scal, reg1, N);
  hipMemsetAsync(reg2, 0, (size_t)N*64*sizeof(float), stream);
  int g2 = (int)(((long long)E*16 + 255)/256);
  k_agg<16,64><<<g2, 256, 0, stream>>>(reg1, er, ec, ew, reg2, E);
  k_decode<<<nb32, 256, 0, stream>>>(reg2, lw, lb, out, N);
}

// Round 2
// 1134.205 us; speedup vs baseline: 4.0027x; 4.0027x over previous
//
#include <hip/hip_runtime.h>
#include <math.h>

#define MINN 1e-15f
#define MAXN 0.996f  // (1 - 4e-3)/sqrt(c), c=1

__device__ __forceinline__ float artanhf_(float v){
  v = fminf(fmaxf(v, -0.9999999f), 0.9999999f);
  return 0.5f*(log1pf(v) - log1pf(-v));
}
__device__ __forceinline__ float grp8(float v){
  v += __shfl_xor(v,1,8); v += __shfl_xor(v,2,8); v += __shfl_xor(v,4,8); return v;
}
__device__ __forceinline__ float grp16(float v){
  v += __shfl_xor(v,1,16); v += __shfl_xor(v,2,16);
  v += __shfl_xor(v,4,16); v += __shfl_xor(v,8,16); return v;
}

// --- transpose+pad w1 -> w1t[k][tx*4+j] = w1[tx+32j][k], k<1440, zero-padded ---
__global__ __launch_bounds__(256) void k_prep_w1t(const float* __restrict__ w1, float* __restrict__ w1t){
  int idx = blockIdx.x*256 + threadIdx.x;        // < 1440*128
  int k = idx >> 7, p = idx & 127;
  int tx = p >> 2, j = p & 3;
  int col = tx + 32*j;
  float v = (k < 1433 && col < 100) ? w1[(size_t)col*1433 + k] : 0.f;
  w1t[idx] = v;
}

// --- hyperbolic biases: hb = proj(expmap0(b)), plus ||hb||^2 ---
__global__ void k_bias(const float* __restrict__ b1, const float* __restrict__ b2,
                       float* __restrict__ hb1, float* __restrict__ hb2, float* __restrict__ scal){
  __shared__ float red[128];
  int t = threadIdx.x;
  float v = (t < 100) ? b1[t] : 0.f;
  red[t] = v*v; __syncthreads();
  for (int s=64;s;s>>=1){ if (t<s) red[t]+=red[t+s]; __syncthreads(); }
  float n2 = red[0]; __syncthreads();
  float n = fmaxf(sqrtf(n2), MINN);
  float s1 = tanhf(n)/n;
  float pn = fmaxf(tanhf(n), MINN);
  float t1 = pn > MAXN ? MAXN/pn : 1.f;
  float hv = s1*t1*v;
  hb1[t] = (t<100) ? hv : 0.f;
  red[t] = (t<100) ? hv*hv : 0.f; __syncthreads();
  for (int s=64;s;s>>=1){ if (t<s) red[t]+=red[t+s]; __syncthreads(); }
  if (t==0) scal[0] = red[0];
  __syncthreads();
  float v2 = (t < 64) ? b2[t] : 0.f;
  red[t] = v2*v2; __syncthreads();
  for (int s=64;s;s>>=1){ if (t<s) red[t]+=red[t+s]; __syncthreads(); }
  float n2b = red[0]; __syncthreads();
  float nb = fmaxf(sqrtf(n2b), MINN);
  float s1b = tanhf(nb)/nb;
  float pnb = fmaxf(tanhf(nb), MINN);
  float t1b = pnb > MAXN ? MAXN/pnb : 1.f;
  float hvb = s1b*t1b*v2;
  if (t < 64) hb2[t] = hvb;
  red[t] = (t<64) ? hvb*hvb : 0.f; __syncthreads();
  for (int s=64;s;s>>=1){ if (t<s) red[t]+=red[t+s]; __syncthreads(); }
  if (t==0) scal[1] = red[0];
}

// --- fused: encode(expmap0+proj) -> mobius_matvec(w1) -> proj -> mobius_add(hb1) -> proj -> logmap0
__global__ __launch_bounds__(256) void k_lin1(
    const float* __restrict__ x, const float* __restrict__ w1t,
    const float* __restrict__ hb1, const float* __restrict__ scal,
    float* __restrict__ xtan1, int N)
{
  __shared__ alignas(16) float xsT[16][36];
  __shared__ alignas(16) float ws[16][128];
  __shared__ float ys[32][132];
  __shared__ float xn2s[32];
  __shared__ float hbs[128];
  int tid = threadIdx.x;
  int tx = tid & 31, ty = tid >> 5;
  int bm = blockIdx.x * 32;
  if (tid < 128) hbs[tid] = hb1[tid];
  float b1sq = scal[0];
  float acc[4][4] = {};
  float xsq0 = 0.f, xsq1 = 0.f;
  int r0 = tid >> 4, k0i = tid & 15;
  for (int k0 = 0; k0 < 1433; k0 += 16) {
    int gk = k0 + k0i;
    bool kv = gk < 1433;
    int gr0 = bm + r0, gr1 = gr0 + 16;
    float v0 = (kv && gr0 < N) ? x[(size_t)gr0*1433 + gk] : 0.f;
    float v1 = (kv && gr1 < N) ? x[(size_t)gr1*1433 + gk] : 0.f;
    xsT[k0i][r0] = v0; xsT[k0i][r0+16] = v1;
    xsq0 += v0*v0; xsq1 += v1*v1;
    const float4* w4 = reinterpret_cast<const float4*>(w1t + (size_t)k0*128);
    float4* s4 = reinterpret_cast<float4*>(&ws[0][0]);
    s4[tid] = w4[tid];
    s4[tid+256] = w4[tid+256];
    __syncthreads();
    #pragma unroll
    for (int k = 0; k < 16; ++k) {
      float4 av = *reinterpret_cast<const float4*>(&xsT[k][ty*4]);
      float4 bv = *reinterpret_cast<const float4*>(&ws[k][tx*4]);
      float a[4] = {av.x, av.y, av.z, av.w};
      float b[4] = {bv.x, bv.y, bv.z, bv.w};
      #pragma unroll
      for (int i=0;i<4;i++)
        #pragma unroll
        for (int j=0;j<4;j++) acc[i][j] += a[i]*b[j];
    }
    __syncthreads();
  }
  xsq0 = grp16(xsq0); xsq1 = grp16(xsq1);
  if ((tid & 15) == 0) { xn2s[r0] = xsq0; xn2s[r0+16] = xsq1; }
  #pragma unroll
  for (int i=0;i<4;i++)
    #pragma unroll
    for (int j=0;j<4;j++)
      ys[4*ty + i][tx + 32*j] = acc[i][j];
  __syncthreads();

  int rr = tid >> 3, g = tid & 7;
  int grow = bm + rr;
  float yn2 = 0.f, dotb = 0.f;
  for (int c = g; c < 100; c += 8) { float v = ys[rr][c]; yn2 += v*v; dotb += v*hbs[c]; }
  yn2 = grp8(yn2); dotb = grp8(dotb);
  float un = fmaxf(sqrtf(xn2s[rr]), MINN);
  float th = tanhf(un);
  float sE = th/un;
  float pn = fmaxf(th, MINN);
  float t1 = pn > MAXN ? MAXN/pn : 1.f;
  float gam = sE*t1;
  float xh = fmaxf(gam*un, MINN);
  float yn = sqrtf(yn2);
  float mxn = fmaxf(gam*yn, MINN);
  float rs = tanhf(mxn/xh*artanhf_(xh))/mxn;
  if (yn2 == 0.f) rs = 0.f;
  float rn = rs*gam*yn;
  float t2 = rn > MAXN ? MAXN/fmaxf(rn,MINN) : 1.f;
  float alpha = t2*rs*gam;
  float x2 = alpha*alpha*yn2;
  float xy = alpha*dotb;
  float den = fmaxf(1.f + 2.f*xy + x2*b1sq, MINN);
  float A = (1.f + 2.f*xy + b1sq)/den, B = (1.f - x2)/den;
  float Aa = A*alpha;
  float on2 = 0.f;
  for (int c=g;c<100;c+=8){ float o = Aa*ys[rr][c] + B*hbs[c]; on2 += o*o; }
  on2 = grp8(on2);
  float on = sqrtf(on2);
  float onc = fmaxf(on, MINN);
  float t3 = onc > MAXN ? MAXN/onc : 1.f;
  float pn3 = fmaxf(t3*on, MINN);
  float fs = artanhf_(pn3)/pn3 * t3;
  if (grow < N)
    for (int c=g;c<100;c+=8){ float o = Aa*ys[rr][c] + B*hbs[c]; xtan1[(size_t)grow*100 + c] = fs*o; }
}

// ===================== CSR build (edges grouped by destination row) =====================
__global__ __launch_bounds__(256) void k_hist(const int* __restrict__ er, int* __restrict__ counts, int E){
  int e = blockIdx.x*256 + threadIdx.x;
  if (e < E) atomicAdd(&counts[er[e]], 1);
}

// block-level exclusive scan: 1024 elements/block (256 thr x 4)
__global__ __launch_bounds__(256) void k_scan1(const int* __restrict__ counts, int* __restrict__ row_start,
                                               int* __restrict__ blksum, int N){
  __shared__ int s[256];
  int t = threadIdx.x;
  int base = blockIdx.x*1024 + t*4;
  int v[4]; int sum = 0;
  #pragma unroll
  for (int i=0;i<4;i++){ v[i] = (base+i < N) ? counts[base+i] : 0; sum += v[i]; }
  s[t] = sum; __syncthreads();
  for (int off=1; off<256; off<<=1){
    int val = (t >= off) ? s[t-off] : 0;
    __syncthreads();
    s[t] += val;
    __syncthreads();
  }
  int run = (t > 0) ? s[t-1] : 0;
  #pragma unroll
  for (int i=0;i<4;i++){ if (base+i < N) row_start[base+i] = run; run += v[i]; }
  if (t == 255) blksum[blockIdx.x] = s[255];
}

__global__ void k_scan2(int* blksum, int nblk){
  int run = 0;
  for (int i=0;i<nblk;i++){ int v = blksum[i]; blksum[i] = run; run += v; }
}

__global__ __launch_bounds__(256) void k_scan3(int* __restrict__ row_start, const int* __restrict__ blksum,
                                               int* __restrict__ cursor, int N){
  int i = blockIdx.x*256 + threadIdx.x;
  if (i < N){ int v = row_start[i] + blksum[i >> 10]; row_start[i] = v; cursor[i] = v; }
}

__global__ __launch_bounds__(256) void k_scatter(const int* __restrict__ er, const int* __restrict__ ec,
    const float* __restrict__ ew, int* __restrict__ cursor,
    int* __restrict__ ecs, float* __restrict__ ews, int E){
  int e = blockIdx.x*256 + threadIdx.x;
  if (e < E){
    int r = er[e];
    int pos = atomicAdd(&cursor[r], 1);
    ecs[pos] = ec[e];
    ews[pos] = ew[e];
  }
}

// ===================== gather aggregation: one wave per row =====================
template<int DD>
__global__ __launch_bounds__(256) void k_agg_gather(
    const float* __restrict__ xt, const int* __restrict__ row_start,
    const int* __restrict__ counts, const int* __restrict__ ecs,
    const float* __restrict__ ews, float* __restrict__ sup, int N)
{
  int row = blockIdx.x*4 + (threadIdx.x >> 6);
  int lane = threadIdx.x & 63;
  if (row >= N) return;
  int start = row_start[row], cnt = counts[row];
  constexpr int D2 = (DD > 64) ? (DD - 64) : 0;
  float acc0 = 0.f, acc1 = 0.f;
  for (int j = 0; j < cnt; j += 64) {
    int cc = 0; float wt = 0.f;
    if (j + lane < cnt) { int idx = start + j + lane; cc = ecs[idx]; wt = ews[idx]; }
    int lim = min(64, cnt - j);
    for (int k = 0; k < lim; ++k) {
      int col = __shfl(cc, k);
      float w  = __shfl(wt, k);
      const float* src = xt + (size_t)col*DD;
      acc0 += w * src[lane];
      if constexpr (D2 > 0) { if (lane < D2) acc1 += w * src[64 + lane]; }
    }
  }
  float* dst = sup + (size_t)row*DD;
  dst[lane] = acc0;
  if constexpr (D2 > 0) { if (lane < D2) dst[64 + lane] = acc1; }
}

// --- fused: proj(expmap0(support1)) -> hyp_act -> mobius_matvec(w2) -> +bias2 -> proj -> logmap0 ---
__global__ __launch_bounds__(256) void k_layer2(
    const float* __restrict__ sup, const float* __restrict__ w2,
    const float* __restrict__ hb2, const float* __restrict__ scal,
    float* __restrict__ xtan2, int N)
{
  __shared__ alignas(16) float w2s[64][100];
  __shared__ float xts[32][105];
  __shared__ float hbs[64];
  int tid = threadIdx.x;
  for (int i = tid; i < 1600; i += 256)
    reinterpret_cast<float4*>(&w2s[0][0])[i] = reinterpret_cast<const float4*>(w2)[i];
  if (tid < 64) hbs[tid] = hb2[tid];
  float b2sq = scal[1];
  __syncthreads();
  int rr = tid >> 3, g = tid & 7;
  int grow = blockIdx.x*32 + rr;
  bool valid = grow < N;
  float sv[13]; float sn2 = 0.f;
  #pragma unroll
  for (int m=0;m<13;m++){
    int j = g + 8*m;
    float v = (valid && j < 100) ? sup[(size_t)grow*100 + j] : 0.f;
    sv[m] = v; sn2 += v*v;
  }
  sn2 = grp8(sn2);
  float snn = fmaxf(sqrtf(sn2), MINN);
  float e1 = tanhf(snn)/snn;
  float pnA = fmaxf(tanhf(snn), MINN);
  float t1 = pnA > MAXN ? MAXN/pnA : 1.f;
  float phi = e1*t1;
  float hn = fmaxf(phi*snn, MINN);
  float lam = artanhf_(hn)/hn;
  float xn2 = 0.f;
  #pragma unroll
  for (int m=0;m<13;m++){
    int j = g + 8*m;
    if (j < 100){ float v = fmaxf(lam*phi*sv[m], 0.f); xts[rr][j] = v; xn2 += v*v; }
  }
  xn2 = grp8(xn2);
  float xn = fmaxf(sqrtf(xn2), MINN);
  float e2 = tanhf(xn)/xn;
  float pnB = fmaxf(tanhf(xn), MINN);
  float t2 = pnB > MAXN ? MAXN/pnB : 1.f;
  float psi = e2*t2;
  __syncthreads();
  float z[8] = {};
  for (int j=0;j<100;j++){
    float xv = xts[rr][j];
    #pragma unroll
    for (int m=0;m<8;m++) z[m] += xv * w2s[g+8*m][j];
  }
  float zn2 = 0.f, dz = 0.f;
  #pragma unroll
  for (int m=0;m<8;m++){ zn2 += z[m]*z[m]; dz += z[m]*hbs[g+8*m]; }
  zn2 = grp8(zn2); dz = grp8(dz);
  float xnh = fmaxf(psi*xn, MINN);
  float zn = sqrtf(zn2);
  float mxn = fmaxf(psi*zn, MINN);
  float rs = tanhf(mxn/xnh*artanhf_(xnh))/mxn;
  if (zn2 == 0.f) rs = 0.f;
  float rn = rs*psi*zn;
  float t3 = rn > MAXN ? MAXN/fmaxf(rn,MINN) : 1.f;
  float alpha = t3*rs*psi;
  float x2 = alpha*alpha*zn2;
  float xy = alpha*dz;
  float den = fmaxf(1.f + 2.f*xy + x2*b2sq, MINN);
  float A = (1.f + 2.f*xy + b2sq)/den, B = (1.f - x2)/den;
  float Aa = A*alpha;
  float ov[8]; float on2 = 0.f;
  #pragma unroll
  for (int m=0;m<8;m++){ ov[m] = Aa*z[m] + B*hbs[g+8*m]; on2 += ov[m]*ov[m]; }
  on2 = grp8(on2);
  float on = sqrtf(on2);
  float onc = fmaxf(on, MINN);
  float t4 = onc > MAXN ? MAXN/onc : 1.f;
  float pn4 = fmaxf(t4*on, MINN);
  float fs = artanhf_(pn4)/pn4 * t4;
  if (valid)
    #pragma unroll
    for (int m=0;m<8;m++) xtan2[(size_t)grow*64 + g + 8*m] = fs*ov[m];
}

// --- fused: proj(expmap0(support2)) -> hyp_act -> logmap0 -> linear(7) + relu -> log_softmax ---
__global__ __launch_bounds__(256) void k_decode(
    const float* __restrict__ sup2, const float* __restrict__ lw,
    const float* __restrict__ lb, float* __restrict__ out, int N)
{
  __shared__ float lws[7][64];
  __shared__ float lbs[7];
  int tid = threadIdx.x;
  for (int i = tid; i < 448; i += 256) lws[i>>6][i&63] = lw[i];
  if (tid < 7) lbs[tid] = lb[tid];
  __syncthreads();
  int rr = tid >> 3, g = tid & 7;
  int grow = blockIdx.x*32 + rr;
  bool valid = grow < N;
  float sv[8]; float sn2 = 0.f;
  #pragma unroll
  for (int m=0;m<8;m++){
    int j = g + 8*m;
    float v = valid ? sup2[(size_t)grow*64 + j] : 0.f;
    sv[m] = v; sn2 += v*v;
  }
  sn2 = grp8(sn2);
  float snn = fmaxf(sqrtf(sn2), MINN);
  float e1 = tanhf(snn)/snn;
  float pnA = fmaxf(tanhf(snn), MINN);
  float t1 = pnA > MAXN ? MAXN/pnA : 1.f;
  float phi = e1*t1;
  float hn = fmaxf(phi*snn, MINN);
  float lam = artanhf_(hn)/hn;
  float xt[8]; float xn2 = 0.f;
  #pragma unroll
  for (int m=0;m<8;m++){ xt[m] = fmaxf(lam*phi*sv[m], 0.f); xn2 += xt[m]*xt[m]; }
  xn2 = grp8(xn2);
  float xn = fmaxf(sqrtf(xn2), MINN);
  float e2 = tanhf(xn)/xn;
  float pnB = fmaxf(tanhf(xn), MINN);
  float t2 = pnB > MAXN ? MAXN/pnB : 1.f;
  float psi = e2*t2;
  float tn = fmaxf(psi*xn, MINN);
  float lam2 = artanhf_(tn)/tn;
  float tc = lam2*psi;
  float lg[7];
  #pragma unroll
  for (int k=0;k<7;k++){
    float p = 0.f;
    #pragma unroll
    for (int m=0;m<8;m++) p += xt[m]*lws[k][g+8*m];
    p = grp8(p) * tc;
    lg[k] = fmaxf(p + lbs[k], 0.f);
  }
  float mx = lg[0];
  #pragma unroll
  for (int k=1;k<7;k++) mx = fmaxf(mx, lg[k]);
  float se = 0.f;
  #pragma unroll
  for (int k=0;k<7;k++) se += expf(lg[k]-mx);
  float lse = logf(se);
  if (valid && g < 7) out[(size_t)grow*7 + g] = lg[g] - mx - lse;
}

extern "C" void kernel_launch(void* const* d_in, const int* in_sizes, int n_in,
                              void* d_out, int out_size, void* d_ws, size_t ws_size,
                              hipStream_t stream)
{
  const float* x  = (const float*)d_in[0];
  const int*   er = (const int*)  d_in[1];
  const int*   ec = (const int*)  d_in[2];
  const float* ew = (const float*)d_in[3];
  const float* w1 = (const float*)d_in[4];
  const float* b1 = (const float*)d_in[5];
  const float* w2 = (const float*)d_in[6];
  const float* b2 = (const float*)d_in[7];
  const float* lw = (const float*)d_in[8];
  const float* lb = (const float*)d_in[9];
  float* out = (float*)d_out;
  int N = in_sizes[0] / 1433;
  int E = in_sizes[1];

  float* W    = (float*)d_ws;
  float* w1t  = W;                       // 184320 floats
  float* hb1  = W + 184320;              // 128
  float* hb2  = W + 184448;              // 64
  float* scal = W + 184512;              // 2
  int*   counts    = (int*)(W + 184576); // N
  int*   row_start = counts + N;         // N
  int*   cursor    = row_start + N;      // N
  int*   blksum    = cursor + N;         // 128
  int*   ecs       = blksum + 128;       // E
  float* ews       = (float*)(ecs + E);  // E
  float* reg1 = ews + E;                 // N*100
  float* reg2 = reg1 + (size_t)N*100;    // N*100

  int nblk_scan = (N + 1023) / 1024;

  // CSR build (independent of lin1; stream-serial is fine)
  hipMemsetAsync(counts, 0, (size_t)N*sizeof(int), stream);
  k_hist<<<(E + 255)/256, 256, 0, stream>>>(er, counts, E);
  k_scan1<<<nblk_scan, 256, 0, stream>>>(counts, row_start, blksum, N);
  k_scan2<<<1, 1, 0, stream>>>(blksum, nblk_scan);
  k_scan3<<<(N + 255)/256, 256, 0, stream>>>(row_start, blksum, cursor, N);
  k_scatter<<<(E + 255)/256, 256, 0, stream>>>(er, ec, ew, cursor, ecs, ews, E);

  k_prep_w1t<<<720, 256, 0, stream>>>(w1, w1t);
  k_bias<<<1, 128, 0, stream>>>(b1, b2, hb1, hb2, scal);
  int nb32 = (N + 31)/32;
  k_lin1<<<nb32, 256, 0, stream>>>(x, w1t, hb1, scal, reg1, N);

  int nbg = (N + 3)/4;
  k_agg_gather<100><<<nbg, 256, 0, stream>>>(reg1, row_start, counts, ecs, ews, reg2, N);
  k_layer2<<<nb32, 256, 0, stream>>>(reg2, w2, hb2, scal, reg1, N);
  k_agg_gather<64><<<nbg, 256, 0, stream>>>(reg1, row_start, counts, ecs, ews, reg2, N);
  k_decode<<<nb32, 256, 0, stream>>>(reg2, lw, lb, out, N);
}

// Round 3
// 1104.582 us; speedup vs baseline: 4.1100x; 1.0268x over previous
//
#include <hip/hip_runtime.h>
#include <math.h>

#define MINN 1e-15f
#define MAXN 0.996f  // (1 - 4e-3)/sqrt(c), c=1

typedef __attribute__((ext_vector_type(8))) short short8;
typedef __attribute__((ext_vector_type(4))) float f32x4;

__device__ __forceinline__ float artanhf_(float v){
  v = fminf(fmaxf(v, -0.9999999f), 0.9999999f);
  return 0.5f*(log1pf(v) - log1pf(-v));
}
__device__ __forceinline__ float grp4(float v){
  v += __shfl_xor(v,1,4); v += __shfl_xor(v,2,4); return v;
}
__device__ __forceinline__ float grp8(float v){
  v += __shfl_xor(v,1,8); v += __shfl_xor(v,2,8); v += __shfl_xor(v,4,8); return v;
}
__device__ __forceinline__ unsigned short f2bf(float f){
  unsigned int u = __float_as_uint(f);
  unsigned int r = (u + 0x7fffu + ((u >> 16) & 1u)) >> 16;  // RNE
  return (unsigned short)r;
}
__device__ __forceinline__ float bf2f(unsigned short h){
  return __uint_as_float(((unsigned int)h) << 16);
}

// --- split w1 (f32 [100][1433]) -> w1hi/w1lo bf16 [112][1440], zero-padded ---
__global__ __launch_bounds__(256) void k_prep_w1b16(const float* __restrict__ w1,
    unsigned short* __restrict__ w1hi, unsigned short* __restrict__ w1lo){
  int idx = blockIdx.x*256 + threadIdx.x;   // < 112*1440
  int col = idx / 1440, k = idx - col*1440;
  float v = (col < 100 && k < 1433) ? w1[(size_t)col*1433 + k] : 0.f;
  unsigned short h = f2bf(v);
  unsigned short lo = f2bf(v - bf2f(h));
  w1hi[idx] = h; w1lo[idx] = lo;
}

// --- hyperbolic biases: hb = proj(expmap0(b)), plus ||hb||^2 ---
__global__ void k_bias(const float* __restrict__ b1, const float* __restrict__ b2,
                       float* __restrict__ hb1, float* __restrict__ hb2, float* __restrict__ scal){
  __shared__ float red[128];
  int t = threadIdx.x;
  float v = (t < 100) ? b1[t] : 0.f;
  red[t] = v*v; __syncthreads();
  for (int s=64;s;s>>=1){ if (t<s) red[t]+=red[t+s]; __syncthreads(); }
  float n2 = red[0]; __syncthreads();
  float n = fmaxf(sqrtf(n2), MINN);
  float s1 = tanhf(n)/n;
  float pn = fmaxf(tanhf(n), MINN);
  float t1 = pn > MAXN ? MAXN/pn : 1.f;
  float hv = s1*t1*v;
  hb1[t] = (t<100) ? hv : 0.f;
  red[t] = (t<100) ? hv*hv : 0.f; __syncthreads();
  for (int s=64;s;s>>=1){ if (t<s) red[t]+=red[t+s]; __syncthreads(); }
  if (t==0) scal[0] = red[0];
  __syncthreads();
  float v2 = (t < 64) ? b2[t] : 0.f;
  red[t] = v2*v2; __syncthreads();
  for (int s=64;s;s>>=1){ if (t<s) red[t]+=red[t+s]; __syncthreads(); }
  float n2b = red[0]; __syncthreads();
  float nb = fmaxf(sqrtf(n2b), MINN);
  float s1b = tanhf(nb)/nb;
  float pnb = fmaxf(tanhf(nb), MINN);
  float t1b = pnb > MAXN ? MAXN/pnb : 1.f;
  float hvb = s1b*t1b*v2;
  if (t < 64) hb2[t] = hvb;
  red[t] = (t<64) ? hvb*hvb : 0.f; __syncthreads();
  for (int s=64;s;s>>=1){ if (t<s) red[t]+=red[t+s]; __syncthreads(); }
  if (t==0) scal[1] = red[0];
}

// --- MFMA split-bf16 fused: encode -> mobius_matvec(w1) -> proj -> mobius_add(hb1) -> proj -> logmap0
// 4 waves, 128 rows x 112 cols per block; per wave 2 row-tiles of 16, 7 col-tiles.
__global__ __launch_bounds__(256) void k_lin1_mfma(
    const float* __restrict__ x, const unsigned short* __restrict__ w1hi,
    const unsigned short* __restrict__ w1lo, const float* __restrict__ hb1,
    const float* __restrict__ scal, float* __restrict__ xtan1, int N)
{
  __shared__ float ys[64][104];
  __shared__ float xn2s[128];
  __shared__ float hbs[104];
  int tid = threadIdx.x;
  int w = tid >> 6, l = tid & 63;
  int lr = l & 15, lg = l >> 4;
  int bm = blockIdx.x * 128;
  if (tid < 104) hbs[tid] = hb1[tid];
  float b1sq = scal[0];

  int r0 = bm + w*32 + lr;
  int r1 = r0 + 16;
  const float* xr0 = x + (size_t)min(r0, N-1)*1433;
  const float* xr1 = x + (size_t)min(r1, N-1)*1433;
  const unsigned short* bh0 = w1hi + lr*1440 + lg*8;
  const unsigned short* bl0 = w1lo + lr*1440 + lg*8;

  f32x4 acc[2][7];
  #pragma unroll
  for (int i=0;i<2;i++)
    #pragma unroll
    for (int t=0;t<7;t++) acc[i][t] = (f32x4){0.f,0.f,0.f,0.f};
  float sq0 = 0.f, sq1 = 0.f;

  for (int kbase = 0; kbase < 1440; kbase += 32) {
    const float* xp0 = xr0 + kbase + lg*8;
    const float* xp1 = xr1 + kbase + lg*8;
    float a0[8], a1[8];
    if (kbase < 1408) {
      #pragma unroll
      for (int j=0;j<8;j++){ a0[j]=xp0[j]; a1[j]=xp1[j]; }
    } else {
      #pragma unroll
      for (int j=0;j<8;j++){
        bool kv = (kbase + lg*8 + j) < 1433;
        a0[j] = kv ? xp0[j] : 0.f;
        a1[j] = kv ? xp1[j] : 0.f;
      }
    }
    short8 ah0, al0, ah1, al1;
    #pragma unroll
    for (int j=0;j<8;j++){
      sq0 += a0[j]*a0[j]; sq1 += a1[j]*a1[j];
      unsigned short h0 = f2bf(a0[j]);
      ah0[j] = (short)h0; al0[j] = (short)f2bf(a0[j] - bf2f(h0));
      unsigned short h1 = f2bf(a1[j]);
      ah1[j] = (short)h1; al1[j] = (short)f2bf(a1[j] - bf2f(h1));
    }
    const short8* bhp = reinterpret_cast<const short8*>(bh0 + kbase);
    const short8* blp = reinterpret_cast<const short8*>(bl0 + kbase);
    #pragma unroll
    for (int t=0;t<7;t++){
      short8 bhv = bhp[t*2880];   // t*16 rows * 1440 = 23040 ushorts = 2880 short8
      short8 blv = blp[t*2880];
      acc[0][t] = __builtin_amdgcn_mfma_f32_16x16x32_bf16(ah0, bhv, acc[0][t], 0,0,0);
      acc[1][t] = __builtin_amdgcn_mfma_f32_16x16x32_bf16(ah1, bhv, acc[1][t], 0,0,0);
      acc[0][t] = __builtin_amdgcn_mfma_f32_16x16x32_bf16(al0, bhv, acc[0][t], 0,0,0);
      acc[1][t] = __builtin_amdgcn_mfma_f32_16x16x32_bf16(al1, bhv, acc[1][t], 0,0,0);
      acc[0][t] = __builtin_amdgcn_mfma_f32_16x16x32_bf16(ah0, blv, acc[0][t], 0,0,0);
      acc[1][t] = __builtin_amdgcn_mfma_f32_16x16x32_bf16(ah1, blv, acc[1][t], 0,0,0);
    }
  }
  sq0 += __shfl_xor(sq0, 16); sq0 += __shfl_xor(sq0, 32);
  sq1 += __shfl_xor(sq1, 16); sq1 += __shfl_xor(sq1, 32);
  if (l < 16) { xn2s[w*32 + l] = sq0; xn2s[w*32 + 16 + l] = sq1; }

  int wl = w & 1;
  for (int p = 0; p < 2; ++p) {
    if ((w >> 1) == p) {
      #pragma unroll
      for (int rt=0;rt<2;rt++)
        #pragma unroll
        for (int t=0;t<7;t++)
          #pragma unroll
          for (int r=0;r<4;r++){
            int col = t*16 + lr;
            if (col < 104) ys[wl*32 + rt*16 + lg*4 + r][col] = acc[rt][t][r];
          }
    }
    __syncthreads();
    int rr = tid >> 2, g = tid & 3;
    int grow = bm + p*64 + rr;
    float yn2 = 0.f, dotb = 0.f;
    for (int c=g;c<100;c+=4){ float v = ys[rr][c]; yn2 += v*v; dotb += v*hbs[c]; }
    yn2 = grp4(yn2); dotb = grp4(dotb);
    float un = fmaxf(sqrtf(xn2s[p*64 + rr]), MINN);
    float th = tanhf(un);
    float sE = th/un;
    float pn = fmaxf(th, MINN);
    float t1 = pn > MAXN ? MAXN/pn : 1.f;
    float gam = sE*t1;
    float xh = fmaxf(gam*un, MINN);
    float yn = sqrtf(yn2);
    float mxn = fmaxf(gam*yn, MINN);
    float rs = tanhf(mxn/xh*artanhf_(xh))/mxn;
    if (yn2 == 0.f) rs = 0.f;
    float rn = rs*gam*yn;
    float t2 = rn > MAXN ? MAXN/fmaxf(rn,MINN) : 1.f;
    float alpha = t2*rs*gam;
    float x2v = alpha*alpha*yn2;
    float xyv = alpha*dotb;
    float den = fmaxf(1.f + 2.f*xyv + x2v*b1sq, MINN);
    float A = (1.f + 2.f*xyv + b1sq)/den, B = (1.f - x2v)/den;
    float Aa = A*alpha;
    float on2 = 0.f;
    for (int c=g;c<100;c+=4){ float o = Aa*ys[rr][c] + B*hbs[c]; on2 += o*o; }
    on2 = grp4(on2);
    float on = sqrtf(on2);
    float onc = fmaxf(on, MINN);
    float t3 = onc > MAXN ? MAXN/onc : 1.f;
    float pn3 = fmaxf(t3*on, MINN);
    float fs = artanhf_(pn3)/pn3 * t3;
    if (grow < N)
      for (int c=g;c<100;c+=4){ float o = Aa*ys[rr][c] + B*hbs[c]; xtan1[(size_t)grow*100 + c] = fs*o; }
    __syncthreads();
  }
}

// ===================== CSR build (edges grouped by destination row) =====================
__global__ __launch_bounds__(256) void k_hist(const int* __restrict__ er, int* __restrict__ counts, int E){
  int e = blockIdx.x*256 + threadIdx.x;
  if (e < E) atomicAdd(&counts[er[e]], 1);
}

__global__ __launch_bounds__(256) void k_scan1(const int* __restrict__ counts, int* __restrict__ row_start,
                                               int* __restrict__ blksum, int N){
  __shared__ int s[256];
  int t = threadIdx.x;
  int base = blockIdx.x*1024 + t*4;
  int v[4]; int sum = 0;
  #pragma unroll
  for (int i=0;i<4;i++){ v[i] = (base+i < N) ? counts[base+i] : 0; sum += v[i]; }
  s[t] = sum; __syncthreads();
  for (int off=1; off<256; off<<=1){
    int val = (t >= off) ? s[t-off] : 0;
    __syncthreads();
    s[t] += val;
    __syncthreads();
  }
  int run = (t > 0) ? s[t-1] : 0;
  #pragma unroll
  for (int i=0;i<4;i++){ if (base+i < N) row_start[base+i] = run; run += v[i]; }
  if (t == 255) blksum[blockIdx.x] = s[255];
}

__global__ void k_scan2(int* blksum, int nblk){
  int run = 0;
  for (int i=0;i<nblk;i++){ int v = blksum[i]; blksum[i] = run; run += v; }
}

__global__ __launch_bounds__(256) void k_scan3(int* __restrict__ row_start, const int* __restrict__ blksum,
                                               int* __restrict__ cursor, int N){
  int i = blockIdx.x*256 + threadIdx.x;
  if (i < N){ int v = row_start[i] + blksum[i >> 10]; row_start[i] = v; cursor[i] = v; }
}

__global__ __launch_bounds__(256) void k_scatter(const int* __restrict__ er, const int* __restrict__ ec,
    const float* __restrict__ ew, int* __restrict__ cursor,
    int* __restrict__ ecs, float* __restrict__ ews, int E){
  int e = blockIdx.x*256 + threadIdx.x;
  if (e < E){
    int r = er[e];
    int pos = atomicAdd(&cursor[r], 1);
    ecs[pos] = ec[e];
    ews[pos] = ew[e];
  }
}

// ===================== gather aggregation: one wave per row =====================
template<int DD>
__global__ __launch_bounds__(256) void k_agg_gather(
    const float* __restrict__ xt, const int* __restrict__ row_start,
    const int* __restrict__ counts, const int* __restrict__ ecs,
    const float* __restrict__ ews, float* __restrict__ sup, int N)
{
  int row = blockIdx.x*4 + (threadIdx.x >> 6);
  int lane = threadIdx.x & 63;
  if (row >= N) return;
  int start = row_start[row], cnt = counts[row];
  constexpr int D2 = (DD > 64) ? (DD - 64) : 0;
  float acc0 = 0.f, acc1 = 0.f;
  for (int j = 0; j < cnt; j += 64) {
    int cc = 0; float wt = 0.f;
    if (j + lane < cnt) { int idx = start + j + lane; cc = ecs[idx]; wt = ews[idx]; }
    int lim = min(64, cnt - j);
    for (int k = 0; k < lim; ++k) {
      int col = __shfl(cc, k);
      float w  = __shfl(wt, k);
      const float* src = xt + (size_t)col*DD;
      acc0 += w * src[lane];
      if constexpr (D2 > 0) { if (lane < D2) acc1 += w * src[64 + lane]; }
    }
  }
  float* dst = sup + (size_t)row*DD;
  dst[lane] = acc0;
  if constexpr (D2 > 0) { if (lane < D2) dst[64 + lane] = acc1; }
}

// --- fused: proj(expmap0(support1)) -> hyp_act -> mobius_matvec(w2) -> +bias2 -> proj -> logmap0 ---
__global__ __launch_bounds__(256) void k_layer2(
    const float* __restrict__ sup, const float* __restrict__ w2,
    const float* __restrict__ hb2, const float* __restrict__ scal,
    float* __restrict__ xtan2, int N)
{
  __shared__ alignas(16) float w2s[64][100];
  __shared__ float xts[32][105];
  __shared__ float hbs[64];
  int tid = threadIdx.x;
  for (int i = tid; i < 1600; i += 256)
    reinterpret_cast<float4*>(&w2s[0][0])[i] = reinterpret_cast<const float4*>(w2)[i];
  if (tid < 64) hbs[tid] = hb2[tid];
  float b2sq = scal[1];
  __syncthreads();
  int rr = tid >> 3, g = tid & 7;
  int grow = blockIdx.x*32 + rr;
  bool valid = grow < N;
  float sv[13]; float sn2 = 0.f;
  #pragma unroll
  for (int m=0;m<13;m++){
    int j = g + 8*m;
    float v = (valid && j < 100) ? sup[(size_t)grow*100 + j] : 0.f;
    sv[m] = v; sn2 += v*v;
  }
  sn2 = grp8(sn2);
  float snn = fmaxf(sqrtf(sn2), MINN);
  float e1 = tanhf(snn)/snn;
  float pnA = fmaxf(tanhf(snn), MINN);
  float t1 = pnA > MAXN ? MAXN/pnA : 1.f;
  float phi = e1*t1;
  float hn = fmaxf(phi*snn, MINN);
  float lam = artanhf_(hn)/hn;
  float xn2 = 0.f;
  #pragma unroll
  for (int m=0;m<13;m++){
    int j = g + 8*m;
    if (j < 100){ float v = fmaxf(lam*phi*sv[m], 0.f); xts[rr][j] = v; xn2 += v*v; }
  }
  xn2 = grp8(xn2);
  float xn = fmaxf(sqrtf(xn2), MINN);
  float e2 = tanhf(xn)/xn;
  float pnB = fmaxf(tanhf(xn), MINN);
  float t2 = pnB > MAXN ? MAXN/pnB : 1.f;
  float psi = e2*t2;
  __syncthreads();
  float z[8] = {};
  for (int j=0;j<100;j++){
    float xv = xts[rr][j];
    #pragma unroll
    for (int m=0;m<8;m++) z[m] += xv * w2s[g+8*m][j];
  }
  float zn2 = 0.f, dz = 0.f;
  #pragma unroll
  for (int m=0;m<8;m++){ zn2 += z[m]*z[m]; dz += z[m]*hbs[g+8*m]; }
  zn2 = grp8(zn2); dz = grp8(dz);
  float xnh = fmaxf(psi*xn, MINN);
  float zn = sqrtf(zn2);
  float mxn = fmaxf(psi*zn, MINN);
  float rs = tanhf(mxn/xnh*artanhf_(xnh))/mxn;
  if (zn2 == 0.f) rs = 0.f;
  float rn = rs*psi*zn;
  float t3 = rn > MAXN ? MAXN/fmaxf(rn,MINN) : 1.f;
  float alpha = t3*rs*psi;
  float x2 = alpha*alpha*zn2;
  float xy = alpha*dz;
  float den = fmaxf(1.f + 2.f*xy + x2*b2sq, MINN);
  float A = (1.f + 2.f*xy + b2sq)/den, B = (1.f - x2)/den;
  float Aa = A*alpha;
  float ov[8]; float on2 = 0.f;
  #pragma unroll
  for (int m=0;m<8;m++){ ov[m] = Aa*z[m] + B*hbs[g+8*m]; on2 += ov[m]*ov[m]; }
  on2 = grp8(on2);
  float on = sqrtf(on2);
  float onc = fmaxf(on, MINN);
  float t4 = onc > MAXN ? MAXN/onc : 1.f;
  float pn4 = fmaxf(t4*on, MINN);
  float fs = artanhf_(pn4)/pn4 * t4;
  if (valid)
    #pragma unroll
    for (int m=0;m<8;m++) xtan2[(size_t)grow*64 + g + 8*m] = fs*ov[m];
}

// --- fused: proj(expmap0(support2)) -> hyp_act -> logmap0 -> linear(7) + relu -> log_softmax ---
__global__ __launch_bounds__(256) void k_decode(
    const float* __restrict__ sup2, const float* __restrict__ lw,
    const float* __restrict__ lb, float* __restrict__ out, int N)
{
  __shared__ float lws[7][64];
  __shared__ float lbs[7];
  int tid = threadIdx.x;
  for (int i = tid; i < 448; i += 256) lws[i>>6][i&63] = lw[i];
  if (tid < 7) lbs[tid] = lb[tid];
  __syncthreads();
  int rr = tid >> 3, g = tid & 7;
  int grow = blockIdx.x*32 + rr;
  bool valid = grow < N;
  float sv[8]; float sn2 = 0.f;
  #pragma unroll
  for (int m=0;m<8;m++){
    int j = g + 8*m;
    float v = valid ? sup2[(size_t)grow*64 + j] : 0.f;
    sv[m] = v; sn2 += v*v;
  }
  sn2 = grp8(sn2);
  float snn = fmaxf(sqrtf(sn2), MINN);
  float e1 = tanhf(snn)/snn;
  float pnA = fmaxf(tanhf(snn), MINN);
  float t1 = pnA > MAXN ? MAXN/pnA : 1.f;
  float phi = e1*t1;
  float hn = fmaxf(phi*snn, MINN);
  float lam = artanhf_(hn)/hn;
  float xt[8]; float xn2 = 0.f;
  #pragma unroll
  for (int m=0;m<8;m++){ xt[m] = fmaxf(lam*phi*sv[m], 0.f); xn2 += xt[m]*xt[m]; }
  xn2 = grp8(xn2);
  float xn = fmaxf(sqrtf(xn2), MINN);
  float e2 = tanhf(xn)/xn;
  float pnB = fmaxf(tanhf(xn), MINN);
  float t2 = pnB > MAXN ? MAXN/pnB : 1.f;
  float psi = e2*t2;
  float tn = fmaxf(psi*xn, MINN);
  float lam2 = artanhf_(tn)/tn;
  float tc = lam2*psi;
  float lg[7];
  #pragma unroll
  for (int k=0;k<7;k++){
    float p = 0.f;
    #pragma unroll
    for (int m=0;m<8;m++) p += xt[m]*lws[k][g+8*m];
    p = grp8(p) * tc;
    lg[k] = fmaxf(p + lbs[k], 0.f);
  }
  float mx = lg[0];
  #pragma unroll
  for (int k=1;k<7;k++) mx = fmaxf(mx, lg[k]);
  float se = 0.f;
  #pragma unroll
  for (int k=0;k<7;k++) se += expf(lg[k]-mx);
  float lse = logf(se);
  if (valid && g < 7) out[(size_t)grow*7 + g] = lg[g] - mx - lse;
}

extern "C" void kernel_launch(void* const* d_in, const int* in_sizes, int n_in,
                              void* d_out, int out_size, void* d_ws, size_t ws_size,
                              hipStream_t stream)
{
  const float* x  = (const float*)d_in[0];
  const int*   er = (const int*)  d_in[1];
  const int*   ec = (const int*)  d_in[2];
  const float* ew = (const float*)d_in[3];
  const float* w1 = (const float*)d_in[4];
  const float* b1 = (const float*)d_in[5];
  const float* w2 = (const float*)d_in[6];
  const float* b2 = (const float*)d_in[7];
  const float* lw = (const float*)d_in[8];
  const float* lb = (const float*)d_in[9];
  float* out = (float*)d_out;
  int N = in_sizes[0] / 1433;
  int E = in_sizes[1];

  float* W = (float*)d_ws;
  float* hb1  = W;                              // 128
  float* hb2  = W + 128;                        // 64
  float* scal = W + 192;                        // 2
  unsigned short* w1hi = (unsigned short*)(W + 256);    // 112*1440 = 161280 ushorts (80640 floats)
  unsigned short* w1lo = (unsigned short*)(W + 80896);  // 80640 floats
  int*   counts    = (int*)(W + 161536);        // N
  int*   row_start = counts + N;                // N
  int*   cursor    = row_start + N;             // N
  int*   blksum    = cursor + N;                // 128
  int*   ecs       = blksum + 128;              // E
  float* ews       = (float*)(ecs + E);         // E
  float* reg1 = ews + E;                        // N*100
  float* reg2 = reg1 + (size_t)N*100;           // N*100

  int nblk_scan = (N + 1023) / 1024;

  // CSR build
  hipMemsetAsync(counts, 0, (size_t)N*sizeof(int), stream);
  k_hist<<<(E + 255)/256, 256, 0, stream>>>(er, counts, E);
  k_scan1<<<nblk_scan, 256, 0, stream>>>(counts, row_start, blksum, N);
  k_scan2<<<1, 1, 0, stream>>>(blksum, nblk_scan);
  k_scan3<<<(N + 255)/256, 256, 0, stream>>>(row_start, blksum, cursor, N);
  k_scatter<<<(E + 255)/256, 256, 0, stream>>>(er, ec, ew, cursor, ecs, ews, E);

  k_prep_w1b16<<<630, 256, 0, stream>>>(w1, w1hi, w1lo);
  k_bias<<<1, 128, 0, stream>>>(b1, b2, hb1, hb2, scal);

  int nb128 = (N + 127)/128;
  k_lin1_mfma<<<nb128, 256, 0, stream>>>(x, w1hi, w1lo, hb1, scal, reg1, N);

  int nbg = (N + 3)/4;
  int nb32 = (N + 31)/32;
  k_agg_gather<100><<<nbg, 256, 0, stream>>>(reg1, row_start, counts, ecs, ews, reg2, N);
  k_layer2<<<nb32, 256, 0, stream>>>(reg2, w2, hb2, scal, reg1, N);
  k_agg_gather<64><<<nbg, 256, 0, stream>>>(reg1, row_start, counts, ecs, ews, reg2, N);
  k_decode<<<nb32, 256, 0, stream>>>(reg2, lw, lb, out, N);
}

// Round 4
// 1040.497 us; speedup vs baseline: 4.3632x; 1.0616x over previous
//
#include <hip/hip_runtime.h>
#include <math.h>

#define MINN 1e-15f
#define MAXN 0.996f  // (1 - 4e-3)/sqrt(c), c=1

typedef __attribute__((ext_vector_type(8))) short short8;
typedef __attribute__((ext_vector_type(4))) float f32x4;

__device__ __forceinline__ float artanhf_(float v){
  v = fminf(fmaxf(v, -0.9999999f), 0.9999999f);
  return 0.5f*(log1pf(v) - log1pf(-v));
}
__device__ __forceinline__ float grp8(float v){
  v += __shfl_xor(v,1,8); v += __shfl_xor(v,2,8); v += __shfl_xor(v,4,8); return v;
}
__device__ __forceinline__ float grp16w(float v){
  v += __shfl_xor(v,1,16); v += __shfl_xor(v,2,16);
  v += __shfl_xor(v,4,16); v += __shfl_xor(v,8,16); return v;
}
__device__ __forceinline__ unsigned short f2bf(float f){
  unsigned int u = __float_as_uint(f);
  unsigned int r = (u + 0x7fffu + ((u >> 16) & 1u)) >> 16;  // RNE
  return (unsigned short)r;
}
__device__ __forceinline__ float bf2f(unsigned short h){
  return __uint_as_float(((unsigned int)h) << 16);
}

// --- split w1 (f32 [100][1433]) -> w1hi/w1lo bf16 [112][1440], zero-padded ---
__global__ __launch_bounds__(256) void k_prep_w1b16(const float* __restrict__ w1,
    unsigned short* __restrict__ w1hi, unsigned short* __restrict__ w1lo){
  int idx = blockIdx.x*256 + threadIdx.x;   // < 112*1440
  int col = idx / 1440, k = idx - col*1440;
  float v = (col < 100 && k < 1433) ? w1[(size_t)col*1433 + k] : 0.f;
  unsigned short h = f2bf(v);
  unsigned short lo = f2bf(v - bf2f(h));
  w1hi[idx] = h; w1lo[idx] = lo;
}

// --- hyperbolic biases: hb = proj(expmap0(b)), plus ||hb||^2 ---
__global__ void k_bias(const float* __restrict__ b1, const float* __restrict__ b2,
                       float* __restrict__ hb1, float* __restrict__ hb2, float* __restrict__ scal){
  __shared__ float red[128];
  int t = threadIdx.x;
  float v = (t < 100) ? b1[t] : 0.f;
  red[t] = v*v; __syncthreads();
  for (int s=64;s;s>>=1){ if (t<s) red[t]+=red[t+s]; __syncthreads(); }
  float n2 = red[0]; __syncthreads();
  float n = fmaxf(sqrtf(n2), MINN);
  float s1 = tanhf(n)/n;
  float pn = fmaxf(tanhf(n), MINN);
  float t1 = pn > MAXN ? MAXN/pn : 1.f;
  float hv = s1*t1*v;
  hb1[t] = (t<100) ? hv : 0.f;
  red[t] = (t<100) ? hv*hv : 0.f; __syncthreads();
  for (int s=64;s;s>>=1){ if (t<s) red[t]+=red[t+s]; __syncthreads(); }
  if (t==0) scal[0] = red[0];
  __syncthreads();
  float v2 = (t < 64) ? b2[t] : 0.f;
  red[t] = v2*v2; __syncthreads();
  for (int s=64;s;s>>=1){ if (t<s) red[t]+=red[t+s]; __syncthreads(); }
  float n2b = red[0]; __syncthreads();
  float nb = fmaxf(sqrtf(n2b), MINN);
  float s1b = tanhf(nb)/nb;
  float pnb = fmaxf(tanhf(nb), MINN);
  float t1b = pnb > MAXN ? MAXN/pnb : 1.f;
  float hvb = s1b*t1b*v2;
  if (t < 64) hb2[t] = hvb;
  red[t] = (t<64) ? hvb*hvb : 0.f; __syncthreads();
  for (int s=64;s;s>>=1){ if (t<s) red[t]+=red[t+s]; __syncthreads(); }
  if (t==0) scal[1] = red[0];
}

// --- MFMA split-bf16 fused lin1, 64 rows/block, 4 waves, shuffle-only epilogue (no LDS) ---
// Wave w owns rows [bm + w*16, +16), all 112 cols (7 col-tiles of 16).
// C/D mapping (HW-verified): lane = (row>>2)*16 + col, reg = row&3.
__global__ __launch_bounds__(256, 4) void k_lin1_mfma(
    const float* __restrict__ x, const unsigned short* __restrict__ w1hi,
    const unsigned short* __restrict__ w1lo, const float* __restrict__ hb1,
    const float* __restrict__ scal, float* __restrict__ xtan1, int N)
{
  int tid = threadIdx.x;
  int w = tid >> 6, l = tid & 63;
  int lr = l & 15, lg = l >> 4;
  int bm = blockIdx.x * 64;
  int row0 = bm + w*16;                 // wave's row-tile base
  int r = row0 + lr;
  const float* xr = x + (size_t)min(r, N-1)*1433 + lg*8;
  const unsigned short* bh0 = w1hi + lr*1440 + lg*8;
  const unsigned short* bl0 = w1lo + lr*1440 + lg*8;
  float b1sq = scal[0];

  f32x4 acc[7];
  #pragma unroll
  for (int t=0;t<7;t++) acc[t] = (f32x4){0.f,0.f,0.f,0.f};
  float sq = 0.f;

  // prefetch k-tile 0
  float xa[8];
  #pragma unroll
  for (int j=0;j<8;j++) xa[j] = xr[j];

  for (int kbase = 0; kbase < 1440; kbase += 32) {
    // prefetch next x k-tile into xb (overlaps with convert+MFMA below)
    float xb[8];
    int nk = kbase + 32;
    if (nk < 1408) {
      const float* xp = xr + nk;
      #pragma unroll
      for (int j=0;j<8;j++) xb[j] = xp[j];
    } else if (nk < 1440) {
      const float* xp = xr + nk;
      #pragma unroll
      for (int j=0;j<8;j++) xb[j] = (lg*8 + j < 25) ? xp[j] : 0.f;  // 1408+25=1433
    } else {
      #pragma unroll
      for (int j=0;j<8;j++) xb[j] = 0.f;
    }

    // convert current x to hi/lo bf16, accumulate row sumsq
    short8 ah, al;
    #pragma unroll
    for (int j=0;j<8;j++){
      float v = xa[j];
      sq += v*v;
      unsigned short h = f2bf(v);
      ah[j] = (short)h;
      al[j] = (short)f2bf(v - bf2f(h));
    }

    const short8* bhp = reinterpret_cast<const short8*>(bh0 + kbase);
    const short8* blp = reinterpret_cast<const short8*>(bl0 + kbase);
    #pragma unroll
    for (int t=0;t<7;t++){
      short8 bhv = bhp[t*2880];   // col-tile stride = 16*1440 shorts = 2880 short8
      short8 blv = blp[t*2880];
      acc[t] = __builtin_amdgcn_mfma_f32_16x16x32_bf16(ah, bhv, acc[t], 0,0,0);
      acc[t] = __builtin_amdgcn_mfma_f32_16x16x32_bf16(al, bhv, acc[t], 0,0,0);
      acc[t] = __builtin_amdgcn_mfma_f32_16x16x32_bf16(ah, blv, acc[t], 0,0,0);
    }
    #pragma unroll
    for (int j=0;j<8;j++) xa[j] = xb[j];
  }

  // row sumsq: combine the 4 k-chunk lanes of each row (lanes with equal l&15)
  sq += __shfl_xor(sq, 16); sq += __shfl_xor(sq, 32);
  // now lane p in [0,16) holds row p's full ||x||^2 (also at p+16,p+32,p+48)

  // per-lane bias values for this lane's column (col = t*16 + lr; hb1 zero-padded to 128)
  float hbv[7];
  #pragma unroll
  for (int t=0;t<7;t++) hbv[t] = hb1[t*16 + lr];

  // epilogue: 4 rows per lane-group, reg r4 holds row 4*(l>>4)+r4
  #pragma unroll
  for (int r4=0;r4<4;r4++){
    int rrow = 4*lg + r4;               // row within wave tile
    float v[7];
    #pragma unroll
    for (int t=0;t<7;t++) v[t] = acc[t][r4];
    float yn2 = 0.f, dotb = 0.f;
    #pragma unroll
    for (int t=0;t<7;t++){ yn2 += v[t]*v[t]; dotb += v[t]*hbv[t]; }
    yn2 = grp16w(yn2); dotb = grp16w(dotb);
    float xn2 = __shfl(sq, rrow);       // row sumsq from lane rrow

    float un = fmaxf(sqrtf(xn2), MINN);
    float th = tanhf(un);
    float sE = th/un;
    float pn = fmaxf(th, MINN);
    float t1 = pn > MAXN ? MAXN/pn : 1.f;
    float gam = sE*t1;
    float xh = fmaxf(gam*un, MINN);
    float yn = sqrtf(yn2);
    float mxn = fmaxf(gam*yn, MINN);
    float rs = tanhf(mxn/xh*artanhf_(xh))/mxn;
    if (yn2 == 0.f) rs = 0.f;
    float rn = rs*gam*yn;
    float t2 = rn > MAXN ? MAXN/fmaxf(rn,MINN) : 1.f;
    float alpha = t2*rs*gam;
    float x2v = alpha*alpha*yn2;
    float xyv = alpha*dotb;
    float den = fmaxf(1.f + 2.f*xyv + x2v*b1sq, MINN);
    float A = (1.f + 2.f*xyv + b1sq)/den, B = (1.f - x2v)/den;
    float Aa = A*alpha;
    float on2 = 0.f;
    float o[7];
    #pragma unroll
    for (int t=0;t<7;t++){ o[t] = Aa*v[t] + B*hbv[t]; on2 += o[t]*o[t]; }
    on2 = grp16w(on2);
    float on = sqrtf(on2);
    float onc = fmaxf(on, MINN);
    float t3 = onc > MAXN ? MAXN/onc : 1.f;
    float pn3 = fmaxf(t3*on, MINN);
    float fs = artanhf_(pn3)/pn3 * t3;

    int grow = row0 + rrow;
    if (grow < N){
      #pragma unroll
      for (int t=0;t<7;t++){
        int c = t*16 + lr;
        if (c < 100) xtan1[(size_t)grow*100 + c] = fs*o[t];
      }
    }
  }
}

// ===================== CSR build (edges grouped by destination row) =====================
__global__ __launch_bounds__(256) void k_hist(const int* __restrict__ er, int* __restrict__ counts, int E){
  int e = blockIdx.x*256 + threadIdx.x;
  if (e < E) atomicAdd(&counts[er[e]], 1);
}

__global__ __launch_bounds__(256) void k_scan1(const int* __restrict__ counts, int* __restrict__ row_start,
                                               int* __restrict__ blksum, int N){
  __shared__ int s[256];
  int t = threadIdx.x;
  int base = blockIdx.x*1024 + t*4;
  int v[4]; int sum = 0;
  #pragma unroll
  for (int i=0;i<4;i++){ v[i] = (base+i < N) ? counts[base+i] : 0; sum += v[i]; }
  s[t] = sum; __syncthreads();
  for (int off=1; off<256; off<<=1){
    int val = (t >= off) ? s[t-off] : 0;
    __syncthreads();
    s[t] += val;
    __syncthreads();
  }
  int run = (t > 0) ? s[t-1] : 0;
  #pragma unroll
  for (int i=0;i<4;i++){ if (base+i < N) row_start[base+i] = run; run += v[i]; }
  if (t == 255) blksum[blockIdx.x] = s[255];
}

__global__ void k_scan2(int* blksum, int nblk){
  int run = 0;
  for (int i=0;i<nblk;i++){ int v = blksum[i]; blksum[i] = run; run += v; }
}

__global__ __launch_bounds__(256) void k_scan3(int* __restrict__ row_start, const int* __restrict__ blksum,
                                               int* __restrict__ cursor, int N){
  int i = blockIdx.x*256 + threadIdx.x;
  if (i < N){ int v = row_start[i] + blksum[i >> 10]; row_start[i] = v; cursor[i] = v; }
}

__global__ __launch_bounds__(256) void k_scatter(const int* __restrict__ er, const int* __restrict__ ec,
    const float* __restrict__ ew, int* __restrict__ cursor,
    int* __restrict__ ecs, float* __restrict__ ews, int E){
  int e = blockIdx.x*256 + threadIdx.x;
  if (e < E){
    int r = er[e];
    int pos = atomicAdd(&cursor[r], 1);
    ecs[pos] = ec[e];
    ews[pos] = ew[e];
  }
}

// ===================== gather aggregation: one wave per row =====================
template<int DD>
__global__ __launch_bounds__(256) void k_agg_gather(
    const float* __restrict__ xt, const int* __restrict__ row_start,
    const int* __restrict__ counts, const int* __restrict__ ecs,
    const float* __restrict__ ews, float* __restrict__ sup, int N)
{
  int row = blockIdx.x*4 + (threadIdx.x >> 6);
  int lane = threadIdx.x & 63;
  if (row >= N) return;
  int start = row_start[row], cnt = counts[row];
  constexpr int D2 = (DD > 64) ? (DD - 64) : 0;
  float acc0 = 0.f, acc1 = 0.f;
  for (int j = 0; j < cnt; j += 64) {
    int cc = 0; float wt = 0.f;
    if (j + lane < cnt) { int idx = start + j + lane; cc = ecs[idx]; wt = ews[idx]; }
    int lim = min(64, cnt - j);
    for (int k = 0; k < lim; ++k) {
      int col = __shfl(cc, k);
      float w  = __shfl(wt, k);
      const float* src = xt + (size_t)col*DD;
      acc0 += w * src[lane];
      if constexpr (D2 > 0) { if (lane < D2) acc1 += w * src[64 + lane]; }
    }
  }
  float* dst = sup + (size_t)row*DD;
  dst[lane] = acc0;
  if constexpr (D2 > 0) { if (lane < D2) dst[64 + lane] = acc1; }
}

// --- fused: proj(expmap0(support1)) -> hyp_act -> mobius_matvec(w2) -> +bias2 -> proj -> logmap0 ---
__global__ __launch_bounds__(256) void k_layer2(
    const float* __restrict__ sup, const float* __restrict__ w2,
    const float* __restrict__ hb2, const float* __restrict__ scal,
    float* __restrict__ xtan2, int N)
{
  __shared__ alignas(16) float w2s[64][100];
  __shared__ float xts[32][105];
  __shared__ float hbs[64];
  int tid = threadIdx.x;
  for (int i = tid; i < 1600; i += 256)
    reinterpret_cast<float4*>(&w2s[0][0])[i] = reinterpret_cast<const float4*>(w2)[i];
  if (tid < 64) hbs[tid] = hb2[tid];
  float b2sq = scal[1];
  __syncthreads();
  int rr = tid >> 3, g = tid & 7;
  int grow = blockIdx.x*32 + rr;
  bool valid = grow < N;
  float sv[13]; float sn2 = 0.f;
  #pragma unroll
  for (int m=0;m<13;m++){
    int j = g + 8*m;
    float v = (valid && j < 100) ? sup[(size_t)grow*100 + j] : 0.f;
    sv[m] = v; sn2 += v*v;
  }
  sn2 = grp8(sn2);
  float snn = fmaxf(sqrtf(sn2), MINN);
  float e1 = tanhf(snn)/snn;
  float pnA = fmaxf(tanhf(snn), MINN);
  float t1 = pnA > MAXN ? MAXN/pnA : 1.f;
  float phi = e1*t1;
  float hn = fmaxf(phi*snn, MINN);
  float lam = artanhf_(hn)/hn;
  float xn2 = 0.f;
  #pragma unroll
  for (int m=0;m<13;m++){
    int j = g + 8*m;
    if (j < 100){ float v = fmaxf(lam*phi*sv[m], 0.f); xts[rr][j] = v; xn2 += v*v; }
  }
  xn2 = grp8(xn2);
  float xn = fmaxf(sqrtf(xn2), MINN);
  float e2 = tanhf(xn)/xn;
  float pnB = fmaxf(tanhf(xn), MINN);
  float t2 = pnB > MAXN ? MAXN/pnB : 1.f;
  float psi = e2*t2;
  __syncthreads();
  float z[8] = {};
  for (int j=0;j<100;j++){
    float xv = xts[rr][j];
    #pragma unroll
    for (int m=0;m<8;m++) z[m] += xv * w2s[g+8*m][j];
  }
  float zn2 = 0.f, dz = 0.f;
  #pragma unroll
  for (int m=0;m<8;m++){ zn2 += z[m]*z[m]; dz += z[m]*hbs[g+8*m]; }
  zn2 = grp8(zn2); dz = grp8(dz);
  float xnh = fmaxf(psi*xn, MINN);
  float zn = sqrtf(zn2);
  float mxn = fmaxf(psi*zn, MINN);
  float rs = tanhf(mxn/xnh*artanhf_(xnh))/mxn;
  if (zn2 == 0.f) rs = 0.f;
  float rn = rs*psi*zn;
  float t3 = rn > MAXN ? MAXN/fmaxf(rn,MINN) : 1.f;
  float alpha = t3*rs*psi;
  float x2 = alpha*alpha*zn2;
  float xy = alpha*dz;
  float den = fmaxf(1.f + 2.f*xy + x2*b2sq, MINN);
  float A = (1.f + 2.f*xy + b2sq)/den, B = (1.f - x2)/den;
  float Aa = A*alpha;
  float ov[8]; float on2 = 0.f;
  #pragma unroll
  for (int m=0;m<8;m++){ ov[m] = Aa*z[m] + B*hbs[g+8*m]; on2 += ov[m]*ov[m]; }
  on2 = grp8(on2);
  float on = sqrtf(on2);
  float onc = fmaxf(on, MINN);
  float t4 = onc > MAXN ? MAXN/onc : 1.f;
  float pn4 = fmaxf(t4*on, MINN);
  float fs = artanhf_(pn4)/pn4 * t4;
  if (valid)
    #pragma unroll
    for (int m=0;m<8;m++) xtan2[(size_t)grow*64 + g + 8*m] = fs*ov[m];
}

// --- fused: proj(expmap0(support2)) -> hyp_act -> logmap0 -> linear(7) + relu -> log_softmax ---
__global__ __launch_bounds__(256) void k_decode(
    const float* __restrict__ sup2, const float* __restrict__ lw,
    const float* __restrict__ lb, float* __restrict__ out, int N)
{
  __shared__ float lws[7][64];
  __shared__ float lbs[7];
  int tid = threadIdx.x;
  for (int i = tid; i < 448; i += 256) lws[i>>6][i&63] = lw[i];
  if (tid < 7) lbs[tid] = lb[tid];
  __syncthreads();
  int rr = tid >> 3, g = tid & 7;
  int grow = blockIdx.x*32 + rr;
  bool valid = grow < N;
  float sv[8]; float sn2 = 0.f;
  #pragma unroll
  for (int m=0;m<8;m++){
    int j = g + 8*m;
    float v = valid ? sup2[(size_t)grow*64 + j] : 0.f;
    sv[m] = v; sn2 += v*v;
  }
  sn2 = grp8(sn2);
  float snn = fmaxf(sqrtf(sn2), MINN);
  float e1 = tanhf(snn)/snn;
  float pnA = fmaxf(tanhf(snn), MINN);
  float t1 = pnA > MAXN ? MAXN/pnA : 1.f;
  float phi = e1*t1;
  float hn = fmaxf(phi*snn, MINN);
  float lam = artanhf_(hn)/hn;
  float xt[8]; float xn2 = 0.f;
  #pragma unroll
  for (int m=0;m<8;m++){ xt[m] = fmaxf(lam*phi*sv[m], 0.f); xn2 += xt[m]*xt[m]; }
  xn2 = grp8(xn2);
  float xn = fmaxf(sqrtf(xn2), MINN);
  float e2 = tanhf(xn)/xn;
  float pnB = fmaxf(tanhf(xn), MINN);
  float t2 = pnB > MAXN ? MAXN/pnB : 1.f;
  float psi = e2*t2;
  float tn = fmaxf(psi*xn, MINN);
  float lam2 = artanhf_(tn)/tn;
  float tc = lam2*psi;
  float lg[7];
  #pragma unroll
  for (int k=0;k<7;k++){
    float p = 0.f;
    #pragma unroll
    for (int m=0;m<8;m++) p += xt[m]*lws[k][g+8*m];
    p = grp8(p) * tc;
    lg[k] = fmaxf(p + lbs[k], 0.f);
  }
  float mx = lg[0];
  #pragma unroll
  for (int k=1;k<7;k++) mx = fmaxf(mx, lg[k]);
  float se = 0.f;
  #pragma unroll
  for (int k=0;k<7;k++) se += expf(lg[k]-mx);
  float lse = logf(se);
  if (valid && g < 7) out[(size_t)grow*7 + g] = lg[g] - mx - lse;
}

extern "C" void kernel_launch(void* const* d_in, const int* in_sizes, int n_in,
                              void* d_out, int out_size, void* d_ws, size_t ws_size,
                              hipStream_t stream)
{
  const float* x  = (const float*)d_in[0];
  const int*   er = (const int*)  d_in[1];
  const int*   ec = (const int*)  d_in[2];
  const float* ew = (const float*)d_in[3];
  const float* w1 = (const float*)d_in[4];
  const float* b1 = (const float*)d_in[5];
  const float* w2 = (const float*)d_in[6];
  const float* b2 = (const float*)d_in[7];
  const float* lw = (const float*)d_in[8];
  const float* lb = (const float*)d_in[9];
  float* out = (float*)d_out;
  int N = in_sizes[0] / 1433;
  int E = in_sizes[1];

  float* W = (float*)d_ws;
  float* hb1  = W;                              // 128
  float* hb2  = W + 128;                        // 64
  float* scal = W + 192;                        // 2
  unsigned short* w1hi = (unsigned short*)(W + 256);    // 112*1440 ushorts
  unsigned short* w1lo = (unsigned short*)(W + 80896);
  int*   counts    = (int*)(W + 161536);        // N
  int*   row_start = counts + N;                // N
  int*   cursor    = row_start + N;             // N
  int*   blksum    = cursor + N;                // 128
  int*   ecs       = blksum + 128;              // E
  float* ews       = (float*)(ecs + E);         // E
  float* reg1 = ews + E;                        // N*100
  float* reg2 = reg1 + (size_t)N*100;           // N*100

  int nblk_scan = (N + 1023) / 1024;

  // CSR build
  hipMemsetAsync(counts, 0, (size_t)N*sizeof(int), stream);
  k_hist<<<(E + 255)/256, 256, 0, stream>>>(er, counts, E);
  k_scan1<<<nblk_scan, 256, 0, stream>>>(counts, row_start, blksum, N);
  k_scan2<<<1, 1, 0, stream>>>(blksum, nblk_scan);
  k_scan3<<<(N + 255)/256, 256, 0, stream>>>(row_start, blksum, cursor, N);
  k_scatter<<<(E + 255)/256, 256, 0, stream>>>(er, ec, ew, cursor, ecs, ews, E);

  k_prep_w1b16<<<630, 256, 0, stream>>>(w1, w1hi, w1lo);
  k_bias<<<1, 128, 0, stream>>>(b1, b2, hb1, hb2, scal);

  int nb64 = (N + 63)/64;
  k_lin1_mfma<<<nb64, 256, 0, stream>>>(x, w1hi, w1lo, hb1, scal, reg1, N);

  int nbg = (N + 3)/4;
  int nb32 = (N + 31)/32;
  k_agg_gather<100><<<nbg, 256, 0, stream>>>(reg1, row_start, counts, ecs, ews, reg2, N);
  k_layer2<<<nb32, 256, 0, stream>>>(reg2, w2, hb2, scal, reg1, N);
  k_agg_gather<64><<<nbg, 256, 0, stream>>>(reg1, row_start, counts, ecs, ews, reg2, N);
  k_decode<<<nb32, 256, 0, stream>>>(reg2, lw, lb, out, N);
}

// Round 5
// 923.597 us; speedup vs baseline: 4.9154x; 1.1266x over previous
//
#include <hip/hip_runtime.h>
#include <math.h>

#define MINN 1e-15f
#define MAXN 0.996f  // (1 - 4e-3)/sqrt(c), c=1

typedef __attribute__((ext_vector_type(8))) short short8;
typedef __attribute__((ext_vector_type(4))) float f32x4;

__device__ __forceinline__ float artanhf_(float v){
  v = fminf(fmaxf(v, -0.9999999f), 0.9999999f);
  return 0.5f*(log1pf(v) - log1pf(-v));
}
__device__ __forceinline__ float grp8(float v){
  v += __shfl_xor(v,1,8); v += __shfl_xor(v,2,8); v += __shfl_xor(v,4,8); return v;
}
__device__ __forceinline__ float grp16w(float v){
  v += __shfl_xor(v,1,16); v += __shfl_xor(v,2,16);
  v += __shfl_xor(v,4,16); v += __shfl_xor(v,8,16); return v;
}
__device__ __forceinline__ unsigned short f2bf(float f){
  unsigned int u = __float_as_uint(f);
  unsigned int r = (u + 0x7fffu + ((u >> 16) & 1u)) >> 16;  // RNE
  return (unsigned short)r;
}
__device__ __forceinline__ float bf2f(unsigned short h){
  return __uint_as_float(((unsigned int)h) << 16);
}

// --- split w1 (f32 [100][1433]) -> w1hi/w1lo bf16 [112][1440], zero-padded ---
__global__ __launch_bounds__(256) void k_prep_w1b16(const float* __restrict__ w1,
    unsigned short* __restrict__ w1hi, unsigned short* __restrict__ w1lo){
  int idx = blockIdx.x*256 + threadIdx.x;   // < 112*1440
  int col = idx / 1440, k = idx - col*1440;
  float v = (col < 100 && k < 1433) ? w1[(size_t)col*1433 + k] : 0.f;
  unsigned short h = f2bf(v);
  unsigned short lo = f2bf(v - bf2f(h));
  w1hi[idx] = h; w1lo[idx] = lo;
}

// --- hyperbolic biases: hb = proj(expmap0(b)), plus ||hb||^2 ---
__global__ void k_bias(const float* __restrict__ b1, const float* __restrict__ b2,
                       float* __restrict__ hb1, float* __restrict__ hb2, float* __restrict__ scal){
  __shared__ float red[128];
  int t = threadIdx.x;
  float v = (t < 100) ? b1[t] : 0.f;
  red[t] = v*v; __syncthreads();
  for (int s=64;s;s>>=1){ if (t<s) red[t]+=red[t+s]; __syncthreads(); }
  float n2 = red[0]; __syncthreads();
  float n = fmaxf(sqrtf(n2), MINN);
  float s1 = tanhf(n)/n;
  float pn = fmaxf(tanhf(n), MINN);
  float t1 = pn > MAXN ? MAXN/pn : 1.f;
  float hv = s1*t1*v;
  hb1[t] = (t<100) ? hv : 0.f;
  red[t] = (t<100) ? hv*hv : 0.f; __syncthreads();
  for (int s=64;s;s>>=1){ if (t<s) red[t]+=red[t+s]; __syncthreads(); }
  if (t==0) scal[0] = red[0];
  __syncthreads();
  float v2 = (t < 64) ? b2[t] : 0.f;
  red[t] = v2*v2; __syncthreads();
  for (int s=64;s;s>>=1){ if (t<s) red[t]+=red[t+s]; __syncthreads(); }
  float n2b = red[0]; __syncthreads();
  float nb = fmaxf(sqrtf(n2b), MINN);
  float s1b = tanhf(nb)/nb;
  float pnb = fmaxf(tanhf(nb), MINN);
  float t1b = pnb > MAXN ? MAXN/pnb : 1.f;
  float hvb = s1b*t1b*v2;
  if (t < 64) hb2[t] = hvb;
  red[t] = (t<64) ? hvb*hvb : 0.f; __syncthreads();
  for (int s=64;s;s>>=1){ if (t<s) red[t]+=red[t+s]; __syncthreads(); }
  if (t==0) scal[1] = red[0];
}

// --- MFMA split-bf16 fused lin1: 128 rows/block, 4 waves, 32 rows (2 row-tiles) per wave.
// B loads batched into register arrays (14 loads in flight -> one vmcnt wait/iter).
// C/D mapping (HW-verified): lane = (row>>2)*16 + col, reg = row&3.
__global__ __launch_bounds__(256) void k_lin1_mfma(
    const float* __restrict__ x, const unsigned short* __restrict__ w1hi,
    const unsigned short* __restrict__ w1lo, const float* __restrict__ hb1,
    const float* __restrict__ scal, float* __restrict__ xtan1, int N)
{
  int tid = threadIdx.x;
  int w = tid >> 6, l = tid & 63;
  int lr = l & 15, lg = l >> 4;
  int bm = blockIdx.x * 128;
  int row0 = bm + w*32;                 // wave's 32-row base
  int ra = row0 + lr, rb = row0 + 16 + lr;
  const float* xr0 = x + (size_t)min(ra, N-1)*1433 + lg*8;
  const float* xr1 = x + (size_t)min(rb, N-1)*1433 + lg*8;
  const unsigned short* bh0 = w1hi + lr*1440 + lg*8;
  const unsigned short* bl0 = w1lo + lr*1440 + lg*8;
  float b1sq = scal[0];

  f32x4 acc[2][7];
  #pragma unroll
  for (int i=0;i<2;i++)
    #pragma unroll
    for (int t=0;t<7;t++) acc[i][t] = (f32x4){0.f,0.f,0.f,0.f};
  float sq0 = 0.f, sq1 = 0.f;

  // prefetch x k-tile 0 (both row-tiles)
  float xa0[8], xa1[8];
  #pragma unroll
  for (int j=0;j<8;j++){ xa0[j] = xr0[j]; xa1[j] = xr1[j]; }

  for (int kbase = 0; kbase < 1440; kbase += 32) {
    // batched B loads (7 col-tiles x hi/lo): issued together, one wait
    short8 bh[7], bl[7];
    const short8* bhp = reinterpret_cast<const short8*>(bh0 + kbase);
    const short8* blp = reinterpret_cast<const short8*>(bl0 + kbase);
    #pragma unroll
    for (int t=0;t<7;t++){ bh[t] = bhp[t*2880]; bl[t] = blp[t*2880]; }

    // prefetch next x k-tile (overlaps with convert+MFMA below)
    float xb0[8], xb1[8];
    int nk = kbase + 32;
    if (nk < 1408) {
      const float* p0 = xr0 + nk; const float* p1 = xr1 + nk;
      #pragma unroll
      for (int j=0;j<8;j++){ xb0[j] = p0[j]; xb1[j] = p1[j]; }
    } else if (nk < 1440) {
      const float* p0 = xr0 + nk; const float* p1 = xr1 + nk;
      #pragma unroll
      for (int j=0;j<8;j++){
        bool kv = (lg*8 + j) < 25;      // 1408+25=1433
        xb0[j] = kv ? p0[j] : 0.f;
        xb1[j] = kv ? p1[j] : 0.f;
      }
    } else {
      #pragma unroll
      for (int j=0;j<8;j++){ xb0[j] = 0.f; xb1[j] = 0.f; }
    }

    // convert current x to hi/lo bf16, accumulate row sumsq
    short8 ah0, al0, ah1, al1;
    #pragma unroll
    for (int j=0;j<8;j++){
      float v0 = xa0[j], v1 = xa1[j];
      sq0 += v0*v0; sq1 += v1*v1;
      unsigned short h0 = f2bf(v0);
      ah0[j] = (short)h0; al0[j] = (short)f2bf(v0 - bf2f(h0));
      unsigned short h1 = f2bf(v1);
      ah1[j] = (short)h1; al1[j] = (short)f2bf(v1 - bf2f(h1));
    }

    #pragma unroll
    for (int t=0;t<7;t++){
      acc[0][t] = __builtin_amdgcn_mfma_f32_16x16x32_bf16(ah0, bh[t], acc[0][t], 0,0,0);
      acc[1][t] = __builtin_amdgcn_mfma_f32_16x16x32_bf16(ah1, bh[t], acc[1][t], 0,0,0);
      acc[0][t] = __builtin_amdgcn_mfma_f32_16x16x32_bf16(al0, bh[t], acc[0][t], 0,0,0);
      acc[1][t] = __builtin_amdgcn_mfma_f32_16x16x32_bf16(al1, bh[t], acc[1][t], 0,0,0);
      acc[0][t] = __builtin_amdgcn_mfma_f32_16x16x32_bf16(ah0, bl[t], acc[0][t], 0,0,0);
      acc[1][t] = __builtin_amdgcn_mfma_f32_16x16x32_bf16(ah1, bl[t], acc[1][t], 0,0,0);
    }
    #pragma unroll
    for (int j=0;j<8;j++){ xa0[j] = xb0[j]; xa1[j] = xb1[j]; }
  }

  // row sumsq: fold the 4 k-chunk lanes of each row
  sq0 += __shfl_xor(sq0, 16); sq0 += __shfl_xor(sq0, 32);
  sq1 += __shfl_xor(sq1, 16); sq1 += __shfl_xor(sq1, 32);
  // lane p in [0,16) holds row p's full ||x||^2 (for its row-tile)

  // per-lane bias values for this lane's column (col = t*16 + lr; hb1 zero-padded to 128)
  float hbv[7];
  #pragma unroll
  for (int t=0;t<7;t++) hbv[t] = hb1[t*16 + lr];

  #pragma unroll
  for (int rt=0;rt<2;rt++){
    #pragma unroll
    for (int r4=0;r4<4;r4++){
      int rrow = 4*lg + r4;             // row within 16-row tile
      float v[7];
      #pragma unroll
      for (int t=0;t<7;t++) v[t] = acc[rt][t][r4];
      float yn2 = 0.f, dotb = 0.f;
      #pragma unroll
      for (int t=0;t<7;t++){ yn2 += v[t]*v[t]; dotb += v[t]*hbv[t]; }
      yn2 = grp16w(yn2); dotb = grp16w(dotb);
      float xn2 = __shfl(rt ? sq1 : sq0, rrow);

      float un = fmaxf(sqrtf(xn2), MINN);
      float th = tanhf(un);
      float sE = th/un;
      float pn = fmaxf(th, MINN);
      float t1 = pn > MAXN ? MAXN/pn : 1.f;
      float gam = sE*t1;
      float xh = fmaxf(gam*un, MINN);
      float yn = sqrtf(yn2);
      float mxn = fmaxf(gam*yn, MINN);
      float rs = tanhf(mxn/xh*artanhf_(xh))/mxn;
      if (yn2 == 0.f) rs = 0.f;
      float rn = rs*gam*yn;
      float t2 = rn > MAXN ? MAXN/fmaxf(rn,MINN) : 1.f;
      float alpha = t2*rs*gam;
      float x2v = alpha*alpha*yn2;
      float xyv = alpha*dotb;
      float den = fmaxf(1.f + 2.f*xyv + x2v*b1sq, MINN);
      float A = (1.f + 2.f*xyv + b1sq)/den, B = (1.f - x2v)/den;
      float Aa = A*alpha;
      float on2 = 0.f;
      float o[7];
      #pragma unroll
      for (int t=0;t<7;t++){ o[t] = Aa*v[t] + B*hbv[t]; on2 += o[t]*o[t]; }
      on2 = grp16w(on2);
      float on = sqrtf(on2);
      float onc = fmaxf(on, MINN);
      float t3 = onc > MAXN ? MAXN/onc : 1.f;
      float pn3 = fmaxf(t3*on, MINN);
      float fs = artanhf_(pn3)/pn3 * t3;

      int grow = row0 + rt*16 + rrow;
      if (grow < N){
        #pragma unroll
        for (int t=0;t<7;t++){
          int c = t*16 + lr;
          if (c < 100) xtan1[(size_t)grow*100 + c] = fs*o[t];
        }
      }
    }
  }
}

// ===================== CSR build (edges grouped by destination row) =====================
__global__ __launch_bounds__(256) void k_hist(const int* __restrict__ er, int* __restrict__ counts, int E){
  int e = blockIdx.x*256 + threadIdx.x;
  if (e < E) atomicAdd(&counts[er[e]], 1);
}

__global__ __launch_bounds__(256) void k_scan1(const int* __restrict__ counts, int* __restrict__ row_start,
                                               int* __restrict__ blksum, int N){
  __shared__ int s[256];
  int t = threadIdx.x;
  int base = blockIdx.x*1024 + t*4;
  int v[4]; int sum = 0;
  #pragma unroll
  for (int i=0;i<4;i++){ v[i] = (base+i < N) ? counts[base+i] : 0; sum += v[i]; }
  s[t] = sum; __syncthreads();
  for (int off=1; off<256; off<<=1){
    int val = (t >= off) ? s[t-off] : 0;
    __syncthreads();
    s[t] += val;
    __syncthreads();
  }
  int run = (t > 0) ? s[t-1] : 0;
  #pragma unroll
  for (int i=0;i<4;i++){ if (base+i < N) row_start[base+i] = run; run += v[i]; }
  if (t == 255) blksum[blockIdx.x] = s[255];
}

__global__ void k_scan2(int* blksum, int nblk){
  int run = 0;
  for (int i=0;i<nblk;i++){ int v = blksum[i]; blksum[i] = run; run += v; }
}

__global__ __launch_bounds__(256) void k_scan3(int* __restrict__ row_start, const int* __restrict__ blksum,
                                               int* __restrict__ cursor, int N){
  int i = blockIdx.x*256 + threadIdx.x;
  if (i < N){ int v = row_start[i] + blksum[i >> 10]; row_start[i] = v; cursor[i] = v; }
}

__global__ __launch_bounds__(256) void k_scatter(const int* __restrict__ er, const int* __restrict__ ec,
    const float* __restrict__ ew, int* __restrict__ cursor,
    int* __restrict__ ecs, float* __restrict__ ews, int E){
  int e = blockIdx.x*256 + threadIdx.x;
  if (e < E){
    int r = er[e];
    int pos = atomicAdd(&cursor[r], 1);
    ecs[pos] = ec[e];
    ews[pos] = ew[e];
  }
}

// ===================== gather aggregation: one wave per row =====================
template<int DD>
__global__ __launch_bounds__(256) void k_agg_gather(
    const float* __restrict__ xt, const int* __restrict__ row_start,
    const int* __restrict__ counts, const int* __restrict__ ecs,
    const float* __restrict__ ews, float* __restrict__ sup, int N)
{
  int row = blockIdx.x*4 + (threadIdx.x >> 6);
  int lane = threadIdx.x & 63;
  if (row >= N) return;
  int start = row_start[row], cnt = counts[row];
  constexpr int D2 = (DD > 64) ? (DD - 64) : 0;
  float acc0 = 0.f, acc1 = 0.f;
  for (int j = 0; j < cnt; j += 64) {
    int cc = 0; float wt = 0.f;
    if (j + lane < cnt) { int idx = start + j + lane; cc = ecs[idx]; wt = ews[idx]; }
    int lim = min(64, cnt - j);
    for (int k = 0; k < lim; ++k) {
      int col = __shfl(cc, k);
      float w  = __shfl(wt, k);
      const float* src = xt + (size_t)col*DD;
      acc0 += w * src[lane];
      if constexpr (D2 > 0) { if (lane < D2) acc1 += w * src[64 + lane]; }
    }
  }
  float* dst = sup + (size_t)row*DD;
  dst[lane] = acc0;
  if constexpr (D2 > 0) { if (lane < D2) dst[64 + lane] = acc1; }
}

// --- fused: proj(expmap0(support1)) -> hyp_act -> mobius_matvec(w2) -> +bias2 -> proj -> logmap0 ---
__global__ __launch_bounds__(256) void k_layer2(
    const float* __restrict__ sup, const float* __restrict__ w2,
    const float* __restrict__ hb2, const float* __restrict__ scal,
    float* __restrict__ xtan2, int N)
{
  __shared__ alignas(16) float w2s[64][100];
  __shared__ float xts[32][105];
  __shared__ float hbs[64];
  int tid = threadIdx.x;
  for (int i = tid; i < 1600; i += 256)
    reinterpret_cast<float4*>(&w2s[0][0])[i] = reinterpret_cast<const float4*>(w2)[i];
  if (tid < 64) hbs[tid] = hb2[tid];
  float b2sq = scal[1];
  __syncthreads();
  int rr = tid >> 3, g = tid & 7;
  int grow = blockIdx.x*32 + rr;
  bool valid = grow < N;
  float sv[13]; float sn2 = 0.f;
  #pragma unroll
  for (int m=0;m<13;m++){
    int j = g + 8*m;
    float v = (valid && j < 100) ? sup[(size_t)grow*100 + j] : 0.f;
    sv[m] = v; sn2 += v*v;
  }
  sn2 = grp8(sn2);
  float snn = fmaxf(sqrtf(sn2), MINN);
  float e1 = tanhf(snn)/snn;
  float pnA = fmaxf(tanhf(snn), MINN);
  float t1 = pnA > MAXN ? MAXN/pnA : 1.f;
  float phi = e1*t1;
  float hn = fmaxf(phi*snn, MINN);
  float lam = artanhf_(hn)/hn;
  float xn2 = 0.f;
  #pragma unroll
  for (int m=0;m<13;m++){
    int j = g + 8*m;
    if (j < 100){ float v = fmaxf(lam*phi*sv[m], 0.f); xts[rr][j] = v; xn2 += v*v; }
  }
  xn2 = grp8(xn2);
  float xn = fmaxf(sqrtf(xn2), MINN);
  float e2 = tanhf(xn)/xn;
  float pnB = fmaxf(tanhf(xn), MINN);
  float t2 = pnB > MAXN ? MAXN/pnB : 1.f;
  float psi = e2*t2;
  __syncthreads();
  float z[8] = {};
  for (int j=0;j<100;j++){
    float xv = xts[rr][j];
    #pragma unroll
    for (int m=0;m<8;m++) z[m] += xv * w2s[g+8*m][j];
  }
  float zn2 = 0.f, dz = 0.f;
  #pragma unroll
  for (int m=0;m<8;m++){ zn2 += z[m]*z[m]; dz += z[m]*hbs[g+8*m]; }
  zn2 = grp8(zn2); dz = grp8(dz);
  float xnh = fmaxf(psi*xn, MINN);
  float zn = sqrtf(zn2);
  float mxn = fmaxf(psi*zn, MINN);
  float rs = tanhf(mxn/xnh*artanhf_(xnh))/mxn;
  if (zn2 == 0.f) rs = 0.f;
  float rn = rs*psi*zn;
  float t3 = rn > MAXN ? MAXN/fmaxf(rn,MINN) : 1.f;
  float alpha = t3*rs*psi;
  float x2 = alpha*alpha*zn2;
  float xy = alpha*dz;
  float den = fmaxf(1.f + 2.f*xy + x2*b2sq, MINN);
  float A = (1.f + 2.f*xy + b2sq)/den, B = (1.f - x2)/den;
  float Aa = A*alpha;
  float ov[8]; float on2 = 0.f;
  #pragma unroll
  for (int m=0;m<8;m++){ ov[m] = Aa*z[m] + B*hbs[g+8*m]; on2 += ov[m]*ov[m]; }
  on2 = grp8(on2);
  float on = sqrtf(on2);
  float onc = fmaxf(on, MINN);
  float t4 = onc > MAXN ? MAXN/onc : 1.f;
  float pn4 = fmaxf(t4*on, MINN);
  float fs = artanhf_(pn4)/pn4 * t4;
  if (valid)
    #pragma unroll
    for (int m=0;m<8;m++) xtan2[(size_t)grow*64 + g + 8*m] = fs*ov[m];
}

// --- fused: proj(expmap0(support2)) -> hyp_act -> logmap0 -> linear(7) + relu -> log_softmax ---
__global__ __launch_bounds__(256) void k_decode(
    const float* __restrict__ sup2, const float* __restrict__ lw,
    const float* __restrict__ lb, float* __restrict__ out, int N)
{
  __shared__ float lws[7][64];
  __shared__ float lbs[7];
  int tid = threadIdx.x;
  for (int i = tid; i < 448; i += 256) lws[i>>6][i&63] = lw[i];
  if (tid < 7) lbs[tid] = lb[tid];
  __syncthreads();
  int rr = tid >> 3, g = tid & 7;
  int grow = blockIdx.x*32 + rr;
  bool valid = grow < N;
  float sv[8]; float sn2 = 0.f;
  #pragma unroll
  for (int m=0;m<8;m++){
    int j = g + 8*m;
    float v = valid ? sup2[(size_t)grow*64 + j] : 0.f;
    sv[m] = v; sn2 += v*v;
  }
  sn2 = grp8(sn2);
  float snn = fmaxf(sqrtf(sn2), MINN);
  float e1 = tanhf(snn)/snn;
  float pnA = fmaxf(tanhf(snn), MINN);
  float t1 = pnA > MAXN ? MAXN/pnA : 1.f;
  float phi = e1*t1;
  float hn = fmaxf(phi*snn, MINN);
  float lam = artanhf_(hn)/hn;
  float xt[8]; float xn2 = 0.f;
  #pragma unroll
  for (int m=0;m<8;m++){ xt[m] = fmaxf(lam*phi*sv[m], 0.f); xn2 += xt[m]*xt[m]; }
  xn2 = grp8(xn2);
  float xn = fmaxf(sqrtf(xn2), MINN);
  float e2 = tanhf(xn)/xn;
  float pnB = fmaxf(tanhf(xn), MINN);
  float t2 = pnB > MAXN ? MAXN/pnB : 1.f;
  float psi = e2*t2;
  float tn = fmaxf(psi*xn, MINN);
  float lam2 = artanhf_(tn)/tn;
  float tc = lam2*psi;
  float lg[7];
  #pragma unroll
  for (int k=0;k<7;k++){
    float p = 0.f;
    #pragma unroll
    for (int m=0;m<8;m++) p += xt[m]*lws[k][g+8*m];
    p = grp8(p) * tc;
    lg[k] = fmaxf(p + lbs[k], 0.f);
  }
  float mx = lg[0];
  #pragma unroll
  for (int k=1;k<7;k++) mx = fmaxf(mx, lg[k]);
  float se = 0.f;
  #pragma unroll
  for (int k=0;k<7;k++) se += expf(lg[k]-mx);
  float lse = logf(se);
  if (valid && g < 7) out[(size_t)grow*7 + g] = lg[g] - mx - lse;
}

extern "C" void kernel_launch(void* const* d_in, const int* in_sizes, int n_in,
                              void* d_out, int out_size, void* d_ws, size_t ws_size,
                              hipStream_t stream)
{
  const float* x  = (const float*)d_in[0];
  const int*   er = (const int*)  d_in[1];
  const int*   ec = (const int*)  d_in[2];
  const float* ew = (const float*)d_in[3];
  const float* w1 = (const float*)d_in[4];
  const float* b1 = (const float*)d_in[5];
  const float* w2 = (const float*)d_in[6];
  const float* b2 = (const float*)d_in[7];
  const float* lw = (const float*)d_in[8];
  const float* lb = (const float*)d_in[9];
  float* out = (float*)d_out;
  int N = in_sizes[0] / 1433;
  int E = in_sizes[1];

  float* W = (float*)d_ws;
  float* hb1  = W;                              // 128
  float* hb2  = W + 128;                        // 64
  float* scal = W + 192;                        // 2
  unsigned short* w1hi = (unsigned short*)(W + 256);    // 112*1440 ushorts
  unsigned short* w1lo = (unsigned short*)(W + 80896);
  int*   counts    = (int*)(W + 161536);        // N
  int*   row_start = counts + N;                // N
  int*   cursor    = row_start + N;             // N
  int*   blksum    = cursor + N;                // 128
  int*   ecs       = blksum + 128;              // E
  float* ews       = (float*)(ecs + E);         // E
  float* reg1 = ews + E;                        // N*100
  float* reg2 = reg1 + (size_t)N*100;           // N*100

  int nblk_scan = (N + 1023) / 1024;

  // CSR build
  hipMemsetAsync(counts, 0, (size_t)N*sizeof(int), stream);
  k_hist<<<(E + 255)/256, 256, 0, stream>>>(er, counts, E);
  k_scan1<<<nblk_scan, 256, 0, stream>>>(counts, row_start, blksum, N);
  k_scan2<<<1, 1, 0, stream>>>(blksum, nblk_scan);
  k_scan3<<<(N + 255)/256, 256, 0, stream>>>(row_start, blksum, cursor, N);
  k_scatter<<<(E + 255)/256, 256, 0, stream>>>(er, ec, ew, cursor, ecs, ews, E);

  k_prep_w1b16<<<630, 256, 0, stream>>>(w1, w1hi, w1lo);
  k_bias<<<1, 128, 0, stream>>>(b1, b2, hb1, hb2, scal);

  int nb128 = (N + 127)/128;
  k_lin1_mfma<<<nb128, 256, 0, stream>>>(x, w1hi, w1lo, hb1, scal, reg1, N);

  int nbg = (N + 3)/4;
  int nb32 = (N + 31)/32;
  k_agg_gather<100><<<nbg, 256, 0, stream>>>(reg1, row_start, counts, ecs, ews, reg2, N);
  k_layer2<<<nb32, 256, 0, stream>>>(reg2, w2, hb2, scal, reg1, N);
  k_agg_gather<64><<<nbg, 256, 0, stream>>>(reg1, row_start, counts, ecs, ews, reg2, N);
  k_decode<<<nb32, 256, 0, stream>>>(reg2, lw, lb, out, N);
}

// Round 6
// 775.372 us; speedup vs baseline: 5.8551x; 1.1912x over previous
//
#include <hip/hip_runtime.h>
#include <math.h>

#define MINN 1e-15f
#define MAXN 0.996f  // (1 - 4e-3)/sqrt(c), c=1

typedef __attribute__((ext_vector_type(8))) short short8;
typedef __attribute__((ext_vector_type(4))) float f32x4;

__device__ __forceinline__ float artanhf_(float v){
  v = fminf(fmaxf(v, -0.9999999f), 0.9999999f);
  return 0.5f*(log1pf(v) - log1pf(-v));
}
__device__ __forceinline__ float grp8(float v){
  v += __shfl_xor(v,1,8); v += __shfl_xor(v,2,8); v += __shfl_xor(v,4,8); return v;
}
__device__ __forceinline__ float grp16w(float v){
  v += __shfl_xor(v,1,16); v += __shfl_xor(v,2,16);
  v += __shfl_xor(v,4,16); v += __shfl_xor(v,8,16); return v;
}
__device__ __forceinline__ unsigned short f2bf(float f){
  unsigned int u = __float_as_uint(f);
  unsigned int r = (u + 0x7fffu + ((u >> 16) & 1u)) >> 16;  // RNE
  return (unsigned short)r;
}
__device__ __forceinline__ float bf2f(unsigned short h){
  return __uint_as_float(((unsigned int)h) << 16);
}

typedef __attribute__((address_space(1))) const unsigned int gu32;
typedef __attribute__((address_space(3))) unsigned int su32;
__device__ __forceinline__ void gload_lds16(const void* g, void* s){
  __builtin_amdgcn_global_load_lds((gu32*)g, (su32*)s, 16, 0, 0);
}

// --- split w1 (f32 [100][1433]) -> w1hi/w1lo bf16 [112][1440], zero-padded ---
__global__ __launch_bounds__(256) void k_prep_w1b16(const float* __restrict__ w1,
    unsigned short* __restrict__ w1hi, unsigned short* __restrict__ w1lo){
  int idx = blockIdx.x*256 + threadIdx.x;   // < 112*1440
  int col = idx / 1440, k = idx - col*1440;
  float v = (col < 100 && k < 1433) ? w1[(size_t)col*1433 + k] : 0.f;
  unsigned short h = f2bf(v);
  unsigned short lo = f2bf(v - bf2f(h));
  w1hi[idx] = h; w1lo[idx] = lo;
}

// --- hyperbolic biases: hb = proj(expmap0(b)), plus ||hb||^2 ---
__global__ void k_bias(const float* __restrict__ b1, const float* __restrict__ b2,
                       float* __restrict__ hb1, float* __restrict__ hb2, float* __restrict__ scal){
  __shared__ float red[128];
  int t = threadIdx.x;
  float v = (t < 100) ? b1[t] : 0.f;
  red[t] = v*v; __syncthreads();
  for (int s=64;s;s>>=1){ if (t<s) red[t]+=red[t+s]; __syncthreads(); }
  float n2 = red[0]; __syncthreads();
  float n = fmaxf(sqrtf(n2), MINN);
  float s1 = tanhf(n)/n;
  float pn = fmaxf(tanhf(n), MINN);
  float t1 = pn > MAXN ? MAXN/pn : 1.f;
  float hv = s1*t1*v;
  hb1[t] = (t<100) ? hv : 0.f;
  red[t] = (t<100) ? hv*hv : 0.f; __syncthreads();
  for (int s=64;s;s>>=1){ if (t<s) red[t]+=red[t+s]; __syncthreads(); }
  if (t==0) scal[0] = red[0];
  __syncthreads();
  float v2 = (t < 64) ? b2[t] : 0.f;
  red[t] = v2*v2; __syncthreads();
  for (int s=64;s;s>>=1){ if (t<s) red[t]+=red[t+s]; __syncthreads(); }
  float n2b = red[0]; __syncthreads();
  float nb = fmaxf(sqrtf(n2b), MINN);
  float s1b = tanhf(nb)/nb;
  float pnb = fmaxf(tanhf(nb), MINN);
  float t1b = pnb > MAXN ? MAXN/pnb : 1.f;
  float hvb = s1b*t1b*v2;
  if (t < 64) hb2[t] = hvb;
  red[t] = (t<64) ? hvb*hvb : 0.f; __syncthreads();
  for (int s=64;s;s>>=1){ if (t<s) red[t]+=red[t+s]; __syncthreads(); }
  if (t==0) scal[1] = red[0];
}

// --- MFMA split-bf16 fused lin1: 128 rows/block, 4 waves x 32 rows (2 row-tiles).
// B k-tile staged in LDS (double-buffered, lane-order layout) via global_load_lds:
//   chunk c (c<7: hi tile t=c; c>=7: lo tile t=c-7), lane l holds 16B =
//   B[t*16 + (l&15)][k0 + (l>>4)*8 .. +8]  at LDS offset (buf*14+c)*1024 + l*16.
// One barrier per k-step: STAGE(next) -> compute(cur) -> __syncthreads().
// C/D mapping (HW-verified): lane = (row>>2)*16 + col, reg = row&3.
__global__ __launch_bounds__(256) void k_lin1_mfma(
    const float* __restrict__ x, const unsigned short* __restrict__ w1hi,
    const unsigned short* __restrict__ w1lo, const float* __restrict__ hb1,
    const float* __restrict__ scal, float* __restrict__ xtan1, int N)
{
  __shared__ alignas(16) char bsm[2*14*1024];   // 28 KB
  int tid = threadIdx.x;
  int w = tid >> 6, l = tid & 63;
  int lr = l & 15, lg = l >> 4;
  int bm = blockIdx.x * 128;
  int row0 = bm + w*32;                 // wave's 32-row base
  int ra = row0 + lr, rb = row0 + 16 + lr;
  const float* xr0 = x + (size_t)min(ra, N-1)*1433 + lg*8;
  const float* xr1 = x + (size_t)min(rb, N-1)*1433 + lg*8;
  float b1sq = scal[0];

  f32x4 acc[2][7];
  #pragma unroll
  for (int i=0;i<2;i++)
    #pragma unroll
    for (int t=0;t<7;t++) acc[i][t] = (f32x4){0.f,0.f,0.f,0.f};
  float sq0 = 0.f, sq1 = 0.f;

  // prologue: stage k-tile 0 into buf 0; prefetch x k-tile 0
  #pragma unroll
  for (int c = 0; c < 14; c += 4){
    int cc = c + w;
    if (cc < 14){
      int t = (cc < 7) ? cc : cc - 7;
      const unsigned short* src = ((cc < 7) ? w1hi : w1lo) + (size_t)(t*16 + lr)*1440 + lg*8;
      gload_lds16(src, bsm + cc*1024);
    }
  }
  float xa0[8], xa1[8];
  #pragma unroll
  for (int j=0;j<8;j++){ xa0[j] = xr0[j]; xa1[j] = xr1[j]; }
  __syncthreads();

  for (int kb = 0; kb < 45; ++kb) {
    int cur = kb & 1, nxt = cur ^ 1;
    int nk = (kb + 1) * 32;

    // prefetch next x k-tile (registers)
    float xb0[8], xb1[8];
    if (nk < 1408) {
      const float* p0 = xr0 + nk; const float* p1 = xr1 + nk;
      #pragma unroll
      for (int j=0;j<8;j++){ xb0[j] = p0[j]; xb1[j] = p1[j]; }
    } else if (nk < 1440) {
      const float* p0 = xr0 + nk; const float* p1 = xr1 + nk;
      #pragma unroll
      for (int j=0;j<8;j++){
        bool kv = (lg*8 + j) < 25;      // 1408+25=1433
        xb0[j] = kv ? p0[j] : 0.f;
        xb1[j] = kv ? p1[j] : 0.f;
      }
    } else {
      #pragma unroll
      for (int j=0;j<8;j++){ xb0[j] = 0.f; xb1[j] = 0.f; }
    }

    // stage next B k-tile into other buffer (async, stays in flight through compute)
    if (kb + 1 < 45){
      #pragma unroll
      for (int c = 0; c < 14; c += 4){
        int cc = c + w;
        if (cc < 14){
          int t = (cc < 7) ? cc : cc - 7;
          const unsigned short* src = ((cc < 7) ? w1hi : w1lo) + (size_t)(t*16 + lr)*1440 + nk + lg*8;
          gload_lds16(src, bsm + (nxt*14 + cc)*1024);
        }
      }
    }

    // convert current x to hi/lo bf16, accumulate row sumsq
    short8 ah0, al0, ah1, al1;
    #pragma unroll
    for (int j=0;j<8;j++){
      float v0 = xa0[j], v1 = xa1[j];
      sq0 += v0*v0; sq1 += v1*v1;
      unsigned short h0 = f2bf(v0);
      ah0[j] = (short)h0; al0[j] = (short)f2bf(v0 - bf2f(h0));
      unsigned short h1 = f2bf(v1);
      ah1[j] = (short)h1; al1[j] = (short)f2bf(v1 - bf2f(h1));
    }

    // read B fragments from LDS (lane-linear -> conflict-free) and MFMA
    const char* base = bsm + cur*14*1024 + (l << 4);
    short8 bh[7], bl[7];
    #pragma unroll
    for (int t=0;t<7;t++){
      bh[t] = *reinterpret_cast<const short8*>(base + t*1024);
      bl[t] = *reinterpret_cast<const short8*>(base + (7+t)*1024);
    }
    #pragma unroll
    for (int t=0;t<7;t++){
      acc[0][t] = __builtin_amdgcn_mfma_f32_16x16x32_bf16(ah0, bh[t], acc[0][t], 0,0,0);
      acc[1][t] = __builtin_amdgcn_mfma_f32_16x16x32_bf16(ah1, bh[t], acc[1][t], 0,0,0);
      acc[0][t] = __builtin_amdgcn_mfma_f32_16x16x32_bf16(al0, bh[t], acc[0][t], 0,0,0);
      acc[1][t] = __builtin_amdgcn_mfma_f32_16x16x32_bf16(al1, bh[t], acc[1][t], 0,0,0);
      acc[0][t] = __builtin_amdgcn_mfma_f32_16x16x32_bf16(ah0, bl[t], acc[0][t], 0,0,0);
      acc[1][t] = __builtin_amdgcn_mfma_f32_16x16x32_bf16(ah1, bl[t], acc[1][t], 0,0,0);
    }
    #pragma unroll
    for (int j=0;j<8;j++){ xa0[j] = xb0[j]; xa1[j] = xb1[j]; }

    // barrier: drains prefetch (vmcnt) + guards LDS WAR (buffer reuse at kb+2)
    __syncthreads();
  }

  // row sumsq: fold the 4 k-chunk lanes of each row
  sq0 += __shfl_xor(sq0, 16); sq0 += __shfl_xor(sq0, 32);
  sq1 += __shfl_xor(sq1, 16); sq1 += __shfl_xor(sq1, 32);

  // per-lane bias values for this lane's column (col = t*16 + lr; hb1 zero-padded to 128)
  float hbv[7];
  #pragma unroll
  for (int t=0;t<7;t++) hbv[t] = hb1[t*16 + lr];

  #pragma unroll
  for (int rt=0;rt<2;rt++){
    #pragma unroll
    for (int r4=0;r4<4;r4++){
      int rrow = 4*lg + r4;             // row within 16-row tile
      float v[7];
      #pragma unroll
      for (int t=0;t<7;t++) v[t] = acc[rt][t][r4];
      float yn2 = 0.f, dotb = 0.f;
      #pragma unroll
      for (int t=0;t<7;t++){ yn2 += v[t]*v[t]; dotb += v[t]*hbv[t]; }
      yn2 = grp16w(yn2); dotb = grp16w(dotb);
      float xn2 = __shfl(rt ? sq1 : sq0, rrow);

      float un = fmaxf(sqrtf(xn2), MINN);
      float th = tanhf(un);
      float sE = th/un;
      float pn = fmaxf(th, MINN);
      float t1 = pn > MAXN ? MAXN/pn : 1.f;
      float gam = sE*t1;
      float xh = fmaxf(gam*un, MINN);
      float yn = sqrtf(yn2);
      float mxn = fmaxf(gam*yn, MINN);
      float rs = tanhf(mxn/xh*artanhf_(xh))/mxn;
      if (yn2 == 0.f) rs = 0.f;
      float rn = rs*gam*yn;
      float t2 = rn > MAXN ? MAXN/fmaxf(rn,MINN) : 1.f;
      float alpha = t2*rs*gam;
      float x2v = alpha*alpha*yn2;
      float xyv = alpha*dotb;
      float den = fmaxf(1.f + 2.f*xyv + x2v*b1sq, MINN);
      float A = (1.f + 2.f*xyv + b1sq)/den, B = (1.f - x2v)/den;
      float Aa = A*alpha;
      float on2 = 0.f;
      float o[7];
      #pragma unroll
      for (int t=0;t<7;t++){ o[t] = Aa*v[t] + B*hbv[t]; on2 += o[t]*o[t]; }
      on2 = grp16w(on2);
      float on = sqrtf(on2);
      float onc = fmaxf(on, MINN);
      float t3 = onc > MAXN ? MAXN/onc : 1.f;
      float pn3 = fmaxf(t3*on, MINN);
      float fs = artanhf_(pn3)/pn3 * t3;

      int grow = row0 + rt*16 + rrow;
      if (grow < N){
        #pragma unroll
        for (int t=0;t<7;t++){
          int c = t*16 + lr;
          if (c < 100) xtan1[(size_t)grow*100 + c] = fs*o[t];
        }
      }
    }
  }
}

// ===================== CSR build (edges grouped by destination row) =====================
__global__ __launch_bounds__(256) void k_hist(const int* __restrict__ er, int* __restrict__ counts, int E){
  int e = blockIdx.x*256 + threadIdx.x;
  if (e < E) atomicAdd(&counts[er[e]], 1);
}

__global__ __launch_bounds__(256) void k_scan1(const int* __restrict__ counts, int* __restrict__ row_start,
                                               int* __restrict__ blksum, int N){
  __shared__ int s[256];
  int t = threadIdx.x;
  int base = blockIdx.x*1024 + t*4;
  int v[4]; int sum = 0;
  #pragma unroll
  for (int i=0;i<4;i++){ v[i] = (base+i < N) ? counts[base+i] : 0; sum += v[i]; }
  s[t] = sum; __syncthreads();
  for (int off=1; off<256; off<<=1){
    int val = (t >= off) ? s[t-off] : 0;
    __syncthreads();
    s[t] += val;
    __syncthreads();
  }
  int run = (t > 0) ? s[t-1] : 0;
  #pragma unroll
  for (int i=0;i<4;i++){ if (base+i < N) row_start[base+i] = run; run += v[i]; }
  if (t == 255) blksum[blockIdx.x] = s[255];
}

__global__ void k_scan2(int* blksum, int nblk){
  int run = 0;
  for (int i=0;i<nblk;i++){ int v = blksum[i]; blksum[i] = run; run += v; }
}

__global__ __launch_bounds__(256) void k_scan3(int* __restrict__ row_start, const int* __restrict__ blksum,
                                               int* __restrict__ cursor, int N){
  int i = blockIdx.x*256 + threadIdx.x;
  if (i < N){ int v = row_start[i] + blksum[i >> 10]; row_start[i] = v; cursor[i] = v; }
}

__global__ __launch_bounds__(256) void k_scatter(const int* __restrict__ er, const int* __restrict__ ec,
    const float* __restrict__ ew, int* __restrict__ cursor,
    int* __restrict__ ecs, float* __restrict__ ews, int E){
  int e = blockIdx.x*256 + threadIdx.x;
  if (e < E){
    int r = er[e];
    int pos = atomicAdd(&cursor[r], 1);
    ecs[pos] = ec[e];
    ews[pos] = ew[e];
  }
}

// ===================== gather aggregation: one wave per row =====================
template<int DD>
__global__ __launch_bounds__(256) void k_agg_gather(
    const float* __restrict__ xt, const int* __restrict__ row_start,
    const int* __restrict__ counts, const int* __restrict__ ecs,
    const float* __restrict__ ews, float* __restrict__ sup, int N)
{
  int row = blockIdx.x*4 + (threadIdx.x >> 6);
  int lane = threadIdx.x & 63;
  if (row >= N) return;
  int start = row_start[row], cnt = counts[row];
  constexpr int D2 = (DD > 64) ? (DD - 64) : 0;
  float acc0 = 0.f, acc1 = 0.f;
  for (int j = 0; j < cnt; j += 64) {
    int cc = 0; float wt = 0.f;
    if (j + lane < cnt) { int idx = start + j + lane; cc = ecs[idx]; wt = ews[idx]; }
    int lim = min(64, cnt - j);
    for (int k = 0; k < lim; ++k) {
      int col = __shfl(cc, k);
      float w  = __shfl(wt, k);
      const float* src = xt + (size_t)col*DD;
      acc0 += w * src[lane];
      if constexpr (D2 > 0) { if (lane < D2) acc1 += w * src[64 + lane]; }
    }
  }
  float* dst = sup + (size_t)row*DD;
  dst[lane] = acc0;
  if constexpr (D2 > 0) { if (lane < D2) dst[64 + lane] = acc1; }
}

// --- fused: proj(expmap0(support1)) -> hyp_act -> mobius_matvec(w2) -> +bias2 -> proj -> logmap0 ---
__global__ __launch_bounds__(256) void k_layer2(
    const float* __restrict__ sup, const float* __restrict__ w2,
    const float* __restrict__ hb2, const float* __restrict__ scal,
    float* __restrict__ xtan2, int N)
{
  __shared__ alignas(16) float w2s[64][100];
  __shared__ float xts[32][105];
  __shared__ float hbs[64];
  int tid = threadIdx.x;
  for (int i = tid; i < 1600; i += 256)
    reinterpret_cast<float4*>(&w2s[0][0])[i] = reinterpret_cast<const float4*>(w2)[i];
  if (tid < 64) hbs[tid] = hb2[tid];
  float b2sq = scal[1];
  __syncthreads();
  int rr = tid >> 3, g = tid & 7;
  int grow = blockIdx.x*32 + rr;
  bool valid = grow < N;
  float sv[13]; float sn2 = 0.f;
  #pragma unroll
  for (int m=0;m<13;m++){
    int j = g + 8*m;
    float v = (valid && j < 100) ? sup[(size_t)grow*100 + j] : 0.f;
    sv[m] = v; sn2 += v*v;
  }
  sn2 = grp8(sn2);
  float snn = fmaxf(sqrtf(sn2), MINN);
  float e1 = tanhf(snn)/snn;
  float pnA = fmaxf(tanhf(snn), MINN);
  float t1 = pnA > MAXN ? MAXN/pnA : 1.f;
  float phi = e1*t1;
  float hn = fmaxf(phi*snn, MINN);
  float lam = artanhf_(hn)/hn;
  float xn2 = 0.f;
  #pragma unroll
  for (int m=0;m<13;m++){
    int j = g + 8*m;
    if (j < 100){ float v = fmaxf(lam*phi*sv[m], 0.f); xts[rr][j] = v; xn2 += v*v; }
  }
  xn2 = grp8(xn2);
  float xn = fmaxf(sqrtf(xn2), MINN);
  float e2 = tanhf(xn)/xn;
  float pnB = fmaxf(tanhf(xn), MINN);
  float t2 = pnB > MAXN ? MAXN/pnB : 1.f;
  float psi = e2*t2;
  __syncthreads();
  float z[8] = {};
  for (int j=0;j<100;j++){
    float xv = xts[rr][j];
    #pragma unroll
    for (int m=0;m<8;m++) z[m] += xv * w2s[g+8*m][j];
  }
  float zn2 = 0.f, dz = 0.f;
  #pragma unroll
  for (int m=0;m<8;m++){ zn2 += z[m]*z[m]; dz += z[m]*hbs[g+8*m]; }
  zn2 = grp8(zn2); dz = grp8(dz);
  float xnh = fmaxf(psi*xn, MINN);
  float zn = sqrtf(zn2);
  float mxn = fmaxf(psi*zn, MINN);
  float rs = tanhf(mxn/xnh*artanhf_(xnh))/mxn;
  if (zn2 == 0.f) rs = 0.f;
  float rn = rs*psi*zn;
  float t3 = rn > MAXN ? MAXN/fmaxf(rn,MINN) : 1.f;
  float alpha = t3*rs*psi;
  float x2 = alpha*alpha*zn2;
  float xy = alpha*dz;
  float den = fmaxf(1.f + 2.f*xy + x2*b2sq, MINN);
  float A = (1.f + 2.f*xy + b2sq)/den, B = (1.f - x2)/den;
  float Aa = A*alpha;
  float ov[8]; float on2 = 0.f;
  #pragma unroll
  for (int m=0;m<8;m++){ ov[m] = Aa*z[m] + B*hbs[g+8*m]; on2 += ov[m]*ov[m]; }
  on2 = grp8(on2);
  float on = sqrtf(on2);
  float onc = fmaxf(on, MINN);
  float t4 = onc > MAXN ? MAXN/onc : 1.f;
  float pn4 = fmaxf(t4*on, MINN);
  float fs = artanhf_(pn4)/pn4 * t4;
  if (valid)
    #pragma unroll
    for (int m=0;m<8;m++) xtan2[(size_t)grow*64 + g + 8*m] = fs*ov[m];
}

// --- fused: proj(expmap0(support2)) -> hyp_act -> logmap0 -> linear(7) + relu -> log_softmax ---
__global__ __launch_bounds__(256) void k_decode(
    const float* __restrict__ sup2, const float* __restrict__ lw,
    const float* __restrict__ lb, float* __restrict__ out, int N)
{
  __shared__ float lws[7][64];
  __shared__ float lbs[7];
  int tid = threadIdx.x;
  for (int i = tid; i < 448; i += 256) lws[i>>6][i&63] = lw[i];
  if (tid < 7) lbs[tid] = lb[tid];
  __syncthreads();
  int rr = tid >> 3, g = tid & 7;
  int grow = blockIdx.x*32 + rr;
  bool valid = grow < N;
  float sv[8]; float sn2 = 0.f;
  #pragma unroll
  for (int m=0;m<8;m++){
    int j = g + 8*m;
    float v = valid ? sup2[(size_t)grow*64 + j] : 0.f;
    sv[m] = v; sn2 += v*v;
  }
  sn2 = grp8(sn2);
  float snn = fmaxf(sqrtf(sn2), MINN);
  float e1 = tanhf(snn)/snn;
  float pnA = fmaxf(tanhf(snn), MINN);
  float t1 = pnA > MAXN ? MAXN/pnA : 1.f;
  float phi = e1*t1;
  float hn = fmaxf(phi*snn, MINN);
  float lam = artanhf_(hn)/hn;
  float xt[8]; float xn2 = 0.f;
  #pragma unroll
  for (int m=0;m<8;m++){ xt[m] = fmaxf(lam*phi*sv[m], 0.f); xn2 += xt[m]*xt[m]; }
  xn2 = grp8(xn2);
  float xn = fmaxf(sqrtf(xn2), MINN);
  float e2 = tanhf(xn)/xn;
  float pnB = fmaxf(tanhf(xn), MINN);
  float t2 = pnB > MAXN ? MAXN/pnB : 1.f;
  float psi = e2*t2;
  float tn = fmaxf(psi*xn, MINN);
  float lam2 = artanhf_(tn)/tn;
  float tc = lam2*psi;
  float lg[7];
  #pragma unroll
  for (int k=0;k<7;k++){
    float p = 0.f;
    #pragma unroll
    for (int m=0;m<8;m++) p += xt[m]*lws[k][g+8*m];
    p = grp8(p) * tc;
    lg[k] = fmaxf(p + lbs[k], 0.f);
  }
  float mx = lg[0];
  #pragma unroll
  for (int k=1;k<7;k++) mx = fmaxf(mx, lg[k]);
  float se = 0.f;
  #pragma unroll
  for (int k=0;k<7;k++) se += expf(lg[k]-mx);
  float lse = logf(se);
  if (valid && g < 7) out[(size_t)grow*7 + g] = lg[g] - mx - lse;
}

extern "C" void kernel_launch(void* const* d_in, const int* in_sizes, int n_in,
                              void* d_out, int out_size, void* d_ws, size_t ws_size,
                              hipStream_t stream)
{
  const float* x  = (const float*)d_in[0];
  const int*   er = (const int*)  d_in[1];
  const int*   ec = (const int*)  d_in[2];
  const float* ew = (const float*)d_in[3];
  const float* w1 = (const float*)d_in[4];
  const float* b1 = (const float*)d_in[5];
  const float* w2 = (const float*)d_in[6];
  const float* b2 = (const float*)d_in[7];
  const float* lw = (const float*)d_in[8];
  const float* lb = (const float*)d_in[9];
  float* out = (float*)d_out;
  int N = in_sizes[0] / 1433;
  int E = in_sizes[1];

  float* W = (float*)d_ws;
  float* hb1  = W;                              // 128
  float* hb2  = W + 128;                        // 64
  float* scal = W + 192;                        // 2
  unsigned short* w1hi = (unsigned short*)(W + 256);    // 112*1440 ushorts
  unsigned short* w1lo = (unsigned short*)(W + 80896);
  int*   counts    = (int*)(W + 161536);        // N
  int*   row_start = counts + N;                // N
  int*   cursor    = row_start + N;             // N
  int*   blksum    = cursor + N;                // 128
  int*   ecs       = blksum + 128;              // E
  float* ews       = (float*)(ecs + E);         // E
  float* reg1 = ews + E;                        // N*100
  float* reg2 = reg1 + (size_t)N*100;           // N*100

  int nblk_scan = (N + 1023) / 1024;

  // CSR build
  hipMemsetAsync(counts, 0, (size_t)N*sizeof(int), stream);
  k_hist<<<(E + 255)/256, 256, 0, stream>>>(er, counts, E);
  k_scan1<<<nblk_scan, 256, 0, stream>>>(counts, row_start, blksum, N);
  k_scan2<<<1, 1, 0, stream>>>(blksum, nblk_scan);
  k_scan3<<<(N + 255)/256, 256, 0, stream>>>(row_start, blksum, cursor, N);
  k_scatter<<<(E + 255)/256, 256, 0, stream>>>(er, ec, ew, cursor, ecs, ews, E);

  k_prep_w1b16<<<630, 256, 0, stream>>>(w1, w1hi, w1lo);
  k_bias<<<1, 128, 0, stream>>>(b1, b2, hb1, hb2, scal);

  int nb128 = (N + 127)/128;
  k_lin1_mfma<<<nb128, 256, 0, stream>>>(x, w1hi, w1lo, hb1, scal, reg1, N);

  int nbg = (N + 3)/4;
  int nb32 = (N + 31)/32;
  k_agg_gather<100><<<nbg, 256, 0, stream>>>(reg1, row_start, counts, ecs, ews, reg2, N);
  k_layer2<<<nb32, 256, 0, stream>>>(reg2, w2, hb2, scal, reg1, N);
  k_agg_gather<64><<<nbg, 256, 0, stream>>>(reg1, row_start, counts, ecs, ews, reg2, N);
  k_decode<<<nb32, 256, 0, stream>>>(reg2, lw, lb, out, N);
}

// Round 7
// 706.218 us; speedup vs baseline: 6.4284x; 1.0979x over previous
//
#include <hip/hip_runtime.h>
#include <math.h>

#define MINN 1e-15f
#define MAXN 0.996f  // (1 - 4e-3)/sqrt(c), c=1

#define KPAD 1472    // 23 * 64

typedef __attribute__((ext_vector_type(8))) short short8;
typedef __attribute__((ext_vector_type(4))) float f32x4;

__device__ __forceinline__ float artanhf_(float v){
  v = fminf(fmaxf(v, -0.9999999f), 0.9999999f);
  return 0.5f*(log1pf(v) - log1pf(-v));
}
__device__ __forceinline__ float grp8(float v){
  v += __shfl_xor(v,1,8); v += __shfl_xor(v,2,8); v += __shfl_xor(v,4,8); return v;
}
__device__ __forceinline__ float grp16w(float v){
  v += __shfl_xor(v,1,16); v += __shfl_xor(v,2,16);
  v += __shfl_xor(v,4,16); v += __shfl_xor(v,8,16); return v;
}
__device__ __forceinline__ unsigned short f2bf(float f){
  unsigned int u = __float_as_uint(f);
  unsigned int r = (u + 0x7fffu + ((u >> 16) & 1u)) >> 16;  // RNE
  return (unsigned short)r;
}
__device__ __forceinline__ float bf2f(unsigned short h){
  return __uint_as_float(((unsigned int)h) << 16);
}

typedef __attribute__((address_space(1))) const unsigned int gu32;
typedef __attribute__((address_space(3))) unsigned int su32;
__device__ __forceinline__ void gload_lds16(const void* g, void* s){
  __builtin_amdgcn_global_load_lds((gu32*)g, (su32*)s, 16, 0, 0);
}

// --- split w1 (f32 [100][1433]) -> w1hi/w1lo bf16 [112][KPAD], zero-padded ---
__global__ __launch_bounds__(256) void k_prep_w1b16(const float* __restrict__ w1,
    unsigned short* __restrict__ w1hi, unsigned short* __restrict__ w1lo){
  int idx = blockIdx.x*256 + threadIdx.x;   // < 112*KPAD
  int col = idx / KPAD, k = idx - col*KPAD;
  float v = (col < 100 && k < 1433) ? w1[(size_t)col*1433 + k] : 0.f;
  unsigned short h = f2bf(v);
  unsigned short lo = f2bf(v - bf2f(h));
  w1hi[idx] = h; w1lo[idx] = lo;
}

// --- hyperbolic biases: hb = proj(expmap0(b)), plus ||hb||^2 ---
__global__ void k_bias(const float* __restrict__ b1, const float* __restrict__ b2,
                       float* __restrict__ hb1, float* __restrict__ hb2, float* __restrict__ scal){
  __shared__ float red[128];
  int t = threadIdx.x;
  float v = (t < 100) ? b1[t] : 0.f;
  red[t] = v*v; __syncthreads();
  for (int s=64;s;s>>=1){ if (t<s) red[t]+=red[t+s]; __syncthreads(); }
  float n2 = red[0]; __syncthreads();
  float n = fmaxf(sqrtf(n2), MINN);
  float s1 = tanhf(n)/n;
  float pn = fmaxf(tanhf(n), MINN);
  float t1 = pn > MAXN ? MAXN/pn : 1.f;
  float hv = s1*t1*v;
  hb1[t] = (t<100) ? hv : 0.f;
  red[t] = (t<100) ? hv*hv : 0.f; __syncthreads();
  for (int s=64;s;s>>=1){ if (t<s) red[t]+=red[t+s]; __syncthreads(); }
  if (t==0) scal[0] = red[0];
  __syncthreads();
  float v2 = (t < 64) ? b2[t] : 0.f;
  red[t] = v2*v2; __syncthreads();
  for (int s=64;s;s>>=1){ if (t<s) red[t]+=red[t+s]; __syncthreads(); }
  float n2b = red[0]; __syncthreads();
  float nb = fmaxf(sqrtf(n2b), MINN);
  float s1b = tanhf(nb)/nb;
  float pnb = fmaxf(tanhf(nb), MINN);
  float t1b = pnb > MAXN ? MAXN/pnb : 1.f;
  float hvb = s1b*t1b*v2;
  if (t < 64) hb2[t] = hvb;
  red[t] = (t<64) ? hvb*hvb : 0.f; __syncthreads();
  for (int s=64;s;s>>=1){ if (t<s) red[t]+=red[t+s]; __syncthreads(); }
  if (t==0) scal[1] = red[0];
}

// --- MFMA split-bf16 fused lin1: 128 rows/block, 4 waves x 32 rows, BK=64.
// LDS: 2 buffers x 28 chunks x 1KB. Chunk cc: half h=cc/14, rem=cc%14,
// hi(rem<7)/lo, tile t=rem%7; lane l holds B[t*16+(l&15)][kb*64+h*32+(l>>4)*8 ..+8].
// One barrier per 64-wide k-step (23 iters). C/D mapping (HW-verified):
// lane = (row>>2)*16 + col, reg = row&3.
__global__ __launch_bounds__(256) void k_lin1_mfma(
    const float* __restrict__ x, const unsigned short* __restrict__ w1hi,
    const unsigned short* __restrict__ w1lo, const float* __restrict__ hb1,
    const float* __restrict__ scal, float* __restrict__ xtan1, int N)
{
  __shared__ alignas(16) char bsm[2*28*1024];   // 56 KB
  int tid = threadIdx.x;
  int w = tid >> 6, l = tid & 63;
  int lr = l & 15, lg = l >> 4;
  int bm = blockIdx.x * 128;
  int row0 = bm + w*32;
  int ra = row0 + lr, rb = row0 + 16 + lr;
  const float* xr0 = x + (size_t)min(ra, N-1)*1433 + lg*8;
  const float* xr1 = x + (size_t)min(rb, N-1)*1433 + lg*8;
  float b1sq = scal[0];

  f32x4 acc[2][7];
  #pragma unroll
  for (int i=0;i<2;i++)
    #pragma unroll
    for (int t=0;t<7;t++) acc[i][t] = (f32x4){0.f,0.f,0.f,0.f};
  float sq0 = 0.f, sq1 = 0.f;

  auto stage = [&](int buf, int kbase){
    #pragma unroll
    for (int c = 0; c < 7; ++c){
      int cc = 7*w + c;                      // [0,28)
      int h = (cc >= 14) ? 1 : 0;
      int rem = cc - h*14;
      int t = (rem < 7) ? rem : rem - 7;
      const unsigned short* arr = (rem < 7) ? w1hi : w1lo;
      const unsigned short* src = arr + (size_t)(t*16 + lr)*KPAD + kbase + h*32 + lg*8;
      gload_lds16(src, bsm + (buf*28 + cc)*1024);
    }
  };
  auto xload = [&](float* d0, float* d1, int kbase){
    #pragma unroll
    for (int h = 0; h < 2; ++h){
      int kk = kbase + h*32;
      const float* p0 = xr0 + kk;
      const float* p1 = xr1 + kk;
      if (kk + 32 <= 1433) {
        #pragma unroll
        for (int j=0;j<8;j++){ d0[h*8+j] = p0[j]; d1[h*8+j] = p1[j]; }
      } else {
        #pragma unroll
        for (int j=0;j<8;j++){
          bool kv = (kk + lg*8 + j) < 1433;
          d0[h*8+j] = kv ? p0[j] : 0.f;
          d1[h*8+j] = kv ? p1[j] : 0.f;
        }
      }
    }
  };

  // prologue
  stage(0, 0);
  float xa0[16], xa1[16];
  xload(xa0, xa1, 0);
  __syncthreads();

  for (int kb = 0; kb < 23; ++kb) {
    int cur = kb & 1, nxt = cur ^ 1;
    int nk = (kb + 1) * 64;

    float xb0[16], xb1[16];
    if (kb + 1 < 23){
      stage(nxt, nk);
      xload(xb0, xb1, nk);
    } else {
      #pragma unroll
      for (int j=0;j<16;j++){ xb0[j] = 0.f; xb1[j] = 0.f; }
    }

    // compute both 32-wide halves of the current 64-wide k-tile
    #pragma unroll
    for (int h = 0; h < 2; ++h){
      short8 ah0, al0, ah1, al1;
      #pragma unroll
      for (int j=0;j<8;j++){
        float v0 = xa0[h*8+j], v1 = xa1[h*8+j];
        sq0 += v0*v0; sq1 += v1*v1;
        unsigned short h0 = f2bf(v0);
        ah0[j] = (short)h0; al0[j] = (short)f2bf(v0 - bf2f(h0));
        unsigned short h1 = f2bf(v1);
        ah1[j] = (short)h1; al1[j] = (short)f2bf(v1 - bf2f(h1));
      }
      const char* base = bsm + (cur*28 + h*14)*1024 + (l << 4);
      short8 bh[7], bl[7];
      #pragma unroll
      for (int t=0;t<7;t++){
        bh[t] = *reinterpret_cast<const short8*>(base + t*1024);
        bl[t] = *reinterpret_cast<const short8*>(base + (7+t)*1024);
      }
      #pragma unroll
      for (int t=0;t<7;t++){
        acc[0][t] = __builtin_amdgcn_mfma_f32_16x16x32_bf16(ah0, bh[t], acc[0][t], 0,0,0);
        acc[1][t] = __builtin_amdgcn_mfma_f32_16x16x32_bf16(ah1, bh[t], acc[1][t], 0,0,0);
        acc[0][t] = __builtin_amdgcn_mfma_f32_16x16x32_bf16(al0, bh[t], acc[0][t], 0,0,0);
        acc[1][t] = __builtin_amdgcn_mfma_f32_16x16x32_bf16(al1, bh[t], acc[1][t], 0,0,0);
        acc[0][t] = __builtin_amdgcn_mfma_f32_16x16x32_bf16(ah0, bl[t], acc[0][t], 0,0,0);
        acc[1][t] = __builtin_amdgcn_mfma_f32_16x16x32_bf16(ah1, bl[t], acc[1][t], 0,0,0);
      }
    }
    #pragma unroll
    for (int j=0;j<16;j++){ xa0[j] = xb0[j]; xa1[j] = xb1[j]; }

    __syncthreads();
  }

  // row sumsq: fold the 4 k-chunk lanes of each row
  sq0 += __shfl_xor(sq0, 16); sq0 += __shfl_xor(sq0, 32);
  sq1 += __shfl_xor(sq1, 16); sq1 += __shfl_xor(sq1, 32);

  float hbv[7];
  #pragma unroll
  for (int t=0;t<7;t++) hbv[t] = hb1[t*16 + lr];

  #pragma unroll
  for (int rt=0;rt<2;rt++){
    #pragma unroll
    for (int r4=0;r4<4;r4++){
      int rrow = 4*lg + r4;
      float v[7];
      #pragma unroll
      for (int t=0;t<7;t++) v[t] = acc[rt][t][r4];
      float yn2 = 0.f, dotb = 0.f;
      #pragma unroll
      for (int t=0;t<7;t++){ yn2 += v[t]*v[t]; dotb += v[t]*hbv[t]; }
      yn2 = grp16w(yn2); dotb = grp16w(dotb);
      float xn2 = __shfl(rt ? sq1 : sq0, rrow);

      float un = fmaxf(sqrtf(xn2), MINN);
      float th = tanhf(un);
      float sE = th/un;
      float pn = fmaxf(th, MINN);
      float t1 = pn > MAXN ? MAXN/pn : 1.f;
      float gam = sE*t1;
      float xh = fmaxf(gam*un, MINN);
      float yn = sqrtf(yn2);
      float mxn = fmaxf(gam*yn, MINN);
      float rs = tanhf(mxn/xh*artanhf_(xh))/mxn;
      if (yn2 == 0.f) rs = 0.f;
      float rn = rs*gam*yn;
      float t2 = rn > MAXN ? MAXN/fmaxf(rn,MINN) : 1.f;
      float alpha = t2*rs*gam;
      float x2v = alpha*alpha*yn2;
      float xyv = alpha*dotb;
      float den = fmaxf(1.f + 2.f*xyv + x2v*b1sq, MINN);
      float A = (1.f + 2.f*xyv + b1sq)/den, B = (1.f - x2v)/den;
      float Aa = A*alpha;
      float on2 = 0.f;
      float o[7];
      #pragma unroll
      for (int t=0;t<7;t++){ o[t] = Aa*v[t] + B*hbv[t]; on2 += o[t]*o[t]; }
      on2 = grp16w(on2);
      float on = sqrtf(on2);
      float onc = fmaxf(on, MINN);
      float t3 = onc > MAXN ? MAXN/onc : 1.f;
      float pn3 = fmaxf(t3*on, MINN);
      float fs = artanhf_(pn3)/pn3 * t3;

      int grow = row0 + rt*16 + rrow;
      if (grow < N){
        #pragma unroll
        for (int t=0;t<7;t++){
          int c = t*16 + lr;
          if (c < 100) xtan1[(size_t)grow*100 + c] = fs*o[t];
        }
      }
    }
  }
}

// ===================== CSR build (edges grouped by destination row) =====================
__global__ __launch_bounds__(256) void k_hist(const int* __restrict__ er, int* __restrict__ counts, int E){
  int e = blockIdx.x*256 + threadIdx.x;
  if (e < E) atomicAdd(&counts[er[e]], 1);
}

__global__ __launch_bounds__(256) void k_scan1(const int* __restrict__ counts, int* __restrict__ row_start,
                                               int* __restrict__ blksum, int N){
  __shared__ int s[256];
  int t = threadIdx.x;
  int base = blockIdx.x*1024 + t*4;
  int v[4]; int sum = 0;
  #pragma unroll
  for (int i=0;i<4;i++){ v[i] = (base+i < N) ? counts[base+i] : 0; sum += v[i]; }
  s[t] = sum; __syncthreads();
  for (int off=1; off<256; off<<=1){
    int val = (t >= off) ? s[t-off] : 0;
    __syncthreads();
    s[t] += val;
    __syncthreads();
  }
  int run = (t > 0) ? s[t-1] : 0;
  #pragma unroll
  for (int i=0;i<4;i++){ if (base+i < N) row_start[base+i] = run; run += v[i]; }
  if (t == 255) blksum[blockIdx.x] = s[255];
}

__global__ void k_scan2(int* blksum, int nblk){
  int run = 0;
  for (int i=0;i<nblk;i++){ int v = blksum[i]; blksum[i] = run; run += v; }
}

__global__ __launch_bounds__(256) void k_scan3(int* __restrict__ row_start, const int* __restrict__ blksum,
                                               int* __restrict__ cursor, int N){
  int i = blockIdx.x*256 + threadIdx.x;
  if (i < N){ int v = row_start[i] + blksum[i >> 10]; row_start[i] = v; cursor[i] = v; }
}

__global__ __launch_bounds__(256) void k_scatter(const int* __restrict__ er, const int* __restrict__ ec,
    const float* __restrict__ ew, int* __restrict__ cursor,
    int* __restrict__ ecs, float* __restrict__ ews, int E){
  int e = blockIdx.x*256 + threadIdx.x;
  if (e < E){
    int r = er[e];
    int pos = atomicAdd(&cursor[r], 1);
    ecs[pos] = ec[e];
    ews[pos] = ew[e];
  }
}

// ===================== gather aggregation: one wave per row, 8-edge batches =====================
template<int DD>
__global__ __launch_bounds__(256) void k_agg_gather(
    const float* __restrict__ xt, const int* __restrict__ row_start,
    const int* __restrict__ counts, const int* __restrict__ ecs,
    const float* __restrict__ ews, float* __restrict__ sup, int N)
{
  int row = blockIdx.x*4 + (threadIdx.x >> 6);
  int lane = threadIdx.x & 63;
  if (row >= N) return;
  int start = row_start[row], cnt = counts[row];
  constexpr int D2 = (DD > 64) ? (DD - 64) : 0;
  float acc0 = 0.f, acc1 = 0.f;
  for (int j = 0; j < cnt; j += 64) {
    int cc = 0; float wt = 0.f;
    if (j + lane < cnt) { int idx = start + j + lane; cc = ecs[idx]; wt = ews[idx]; }
    int lim = min(64, cnt - j);
    int k = 0;
    // 8-edge batches: 8(+8) independent gather loads in flight, one wait
    for (; k + 8 <= lim; k += 8) {
      const float* s0; const float* s1; const float* s2; const float* s3;
      const float* s4; const float* s5; const float* s6; const float* s7;
      float w0,w1,w2,w3,w4,w5,w6,w7;
      s0 = xt + (size_t)__shfl(cc,k+0)*DD; w0 = __shfl(wt,k+0);
      s1 = xt + (size_t)__shfl(cc,k+1)*DD; w1 = __shfl(wt,k+1);
      s2 = xt + (size_t)__shfl(cc,k+2)*DD; w2 = __shfl(wt,k+2);
      s3 = xt + (size_t)__shfl(cc,k+3)*DD; w3 = __shfl(wt,k+3);
      s4 = xt + (size_t)__shfl(cc,k+4)*DD; w4 = __shfl(wt,k+4);
      s5 = xt + (size_t)__shfl(cc,k+5)*DD; w5 = __shfl(wt,k+5);
      s6 = xt + (size_t)__shfl(cc,k+6)*DD; w6 = __shfl(wt,k+6);
      s7 = xt + (size_t)__shfl(cc,k+7)*DD; w7 = __shfl(wt,k+7);
      float v0 = s0[lane], v1 = s1[lane], v2 = s2[lane], v3 = s3[lane];
      float v4 = s4[lane], v5 = s5[lane], v6 = s6[lane], v7 = s7[lane];
      if constexpr (D2 > 0) {
        if (lane < D2) {
          float u0 = s0[64+lane], u1 = s1[64+lane], u2 = s2[64+lane], u3 = s3[64+lane];
          float u4 = s4[64+lane], u5 = s5[64+lane], u6 = s6[64+lane], u7 = s7[64+lane];
          acc1 += w0*u0; acc1 += w1*u1; acc1 += w2*u2; acc1 += w3*u3;
          acc1 += w4*u4; acc1 += w5*u5; acc1 += w6*u6; acc1 += w7*u7;
        }
      }
      acc0 += w0*v0; acc0 += w1*v1; acc0 += w2*v2; acc0 += w3*v3;
      acc0 += w4*v4; acc0 += w5*v5; acc0 += w6*v6; acc0 += w7*v7;
    }
    for (; k < lim; ++k) {
      int col = __shfl(cc, k);
      float w  = __shfl(wt, k);
      const float* src = xt + (size_t)col*DD;
      acc0 += w * src[lane];
      if constexpr (D2 > 0) { if (lane < D2) acc1 += w * src[64 + lane]; }
    }
  }
  float* dst = sup + (size_t)row*DD;
  dst[lane] = acc0;
  if constexpr (D2 > 0) { if (lane < D2) dst[64 + lane] = acc1; }
}

// --- fused: proj(expmap0(support1)) -> hyp_act -> mobius_matvec(w2) -> +bias2 -> proj -> logmap0 ---
__global__ __launch_bounds__(256) void k_layer2(
    const float* __restrict__ sup, const float* __restrict__ w2,
    const float* __restrict__ hb2, const float* __restrict__ scal,
    float* __restrict__ xtan2, int N)
{
  __shared__ alignas(16) float w2s[64][100];
  __shared__ float xts[32][105];
  __shared__ float hbs[64];
  int tid = threadIdx.x;
  for (int i = tid; i < 1600; i += 256)
    reinterpret_cast<float4*>(&w2s[0][0])[i] = reinterpret_cast<const float4*>(w2)[i];
  if (tid < 64) hbs[tid] = hb2[tid];
  float b2sq = scal[1];
  __syncthreads();
  int rr = tid >> 3, g = tid & 7;
  int grow = blockIdx.x*32 + rr;
  bool valid = grow < N;
  float sv[13]; float sn2 = 0.f;
  #pragma unroll
  for (int m=0;m<13;m++){
    int j = g + 8*m;
    float v = (valid && j < 100) ? sup[(size_t)grow*100 + j] : 0.f;
    sv[m] = v; sn2 += v*v;
  }
  sn2 = grp8(sn2);
  float snn = fmaxf(sqrtf(sn2), MINN);
  float e1 = tanhf(snn)/snn;
  float pnA = fmaxf(tanhf(snn), MINN);
  float t1 = pnA > MAXN ? MAXN/pnA : 1.f;
  float phi = e1*t1;
  float hn = fmaxf(phi*snn, MINN);
  float lam = artanhf_(hn)/hn;
  float xn2 = 0.f;
  #pragma unroll
  for (int m=0;m<13;m++){
    int j = g + 8*m;
    if (j < 100){ float v = fmaxf(lam*phi*sv[m], 0.f); xts[rr][j] = v; xn2 += v*v; }
  }
  xn2 = grp8(xn2);
  float xn = fmaxf(sqrtf(xn2), MINN);
  float e2 = tanhf(xn)/xn;
  float pnB = fmaxf(tanhf(xn), MINN);
  float t2 = pnB > MAXN ? MAXN/pnB : 1.f;
  float psi = e2*t2;
  __syncthreads();
  float z[8] = {};
  for (int j=0;j<100;j++){
    float xv = xts[rr][j];
    #pragma unroll
    for (int m=0;m<8;m++) z[m] += xv * w2s[g+8*m][j];
  }
  float zn2 = 0.f, dz = 0.f;
  #pragma unroll
  for (int m=0;m<8;m++){ zn2 += z[m]*z[m]; dz += z[m]*hbs[g+8*m]; }
  zn2 = grp8(zn2); dz = grp8(dz);
  float xnh = fmaxf(psi*xn, MINN);
  float zn = sqrtf(zn2);
  float mxn = fmaxf(psi*zn, MINN);
  float rs = tanhf(mxn/xnh*artanhf_(xnh))/mxn;
  if (zn2 == 0.f) rs = 0.f;
  float rn = rs*psi*zn;
  float t3 = rn > MAXN ? MAXN/fmaxf(rn,MINN) : 1.f;
  float alpha = t3*rs*psi;
  float x2 = alpha*alpha*zn2;
  float xy = alpha*dz;
  float den = fmaxf(1.f + 2.f*xy + x2*b2sq, MINN);
  float A = (1.f + 2.f*xy + b2sq)/den, B = (1.f - x2)/den;
  float Aa = A*alpha;
  float ov[8]; float on2 = 0.f;
  #pragma unroll
  for (int m=0;m<8;m++){ ov[m] = Aa*z[m] + B*hbs[g+8*m]; on2 += ov[m]*ov[m]; }
  on2 = grp8(on2);
  float on = sqrtf(on2);
  float onc = fmaxf(on, MINN);
  float t4 = onc > MAXN ? MAXN/onc : 1.f;
  float pn4 = fmaxf(t4*on, MINN);
  float fs = artanhf_(pn4)/pn4 * t4;
  if (valid)
    #pragma unroll
    for (int m=0;m<8;m++) xtan2[(size_t)grow*64 + g + 8*m] = fs*ov[m];
}

// --- fused: proj(expmap0(support2)) -> hyp_act -> logmap0 -> linear(7) + relu -> log_softmax ---
__global__ __launch_bounds__(256) void k_decode(
    const float* __restrict__ sup2, const float* __restrict__ lw,
    const float* __restrict__ lb, float* __restrict__ out, int N)
{
  __shared__ float lws[7][64];
  __shared__ float lbs[7];
  int tid = threadIdx.x;
  for (int i = tid; i < 448; i += 256) lws[i>>6][i&63] = lw[i];
  if (tid < 7) lbs[tid] = lb[tid];
  __syncthreads();
  int rr = tid >> 3, g = tid & 7;
  int grow = blockIdx.x*32 + rr;
  bool valid = grow < N;
  float sv[8]; float sn2 = 0.f;
  #pragma unroll
  for (int m=0;m<8;m++){
    int j = g + 8*m;
    float v = valid ? sup2[(size_t)grow*64 + j] : 0.f;
    sv[m] = v; sn2 += v*v;
  }
  sn2 = grp8(sn2);
  float snn = fmaxf(sqrtf(sn2), MINN);
  float e1 = tanhf(snn)/snn;
  float pnA = fmaxf(tanhf(snn), MINN);
  float t1 = pnA > MAXN ? MAXN/pnA : 1.f;
  float phi = e1*t1;
  float hn = fmaxf(phi*snn, MINN);
  float lam = artanhf_(hn)/hn;
  float xt[8]; float xn2 = 0.f;
  #pragma unroll
  for (int m=0;m<8;m++){ xt[m] = fmaxf(lam*phi*sv[m], 0.f); xn2 += xt[m]*xt[m]; }
  xn2 = grp8(xn2);
  float xn = fmaxf(sqrtf(xn2), MINN);
  float e2 = tanhf(xn)/xn;
  float pnB = fmaxf(tanhf(xn), MINN);
  float t2 = pnB > MAXN ? MAXN/pnB : 1.f;
  float psi = e2*t2;
  float tn = fmaxf(psi*xn, MINN);
  float lam2 = artanhf_(tn)/tn;
  float tc = lam2*psi;
  float lg[7];
  #pragma unroll
  for (int k=0;k<7;k++){
    float p = 0.f;
    #pragma unroll
    for (int m=0;m<8;m++) p += xt[m]*lws[k][g+8*m];
    p = grp8(p) * tc;
    lg[k] = fmaxf(p + lbs[k], 0.f);
  }
  float mx = lg[0];
  #pragma unroll
  for (int k=1;k<7;k++) mx = fmaxf(mx, lg[k]);
  float se = 0.f;
  #pragma unroll
  for (int k=0;k<7;k++) se += expf(lg[k]-mx);
  float lse = logf(se);
  if (valid && g < 7) out[(size_t)grow*7 + g] = lg[g] - mx - lse;
}

extern "C" void kernel_launch(void* const* d_in, const int* in_sizes, int n_in,
                              void* d_out, int out_size, void* d_ws, size_t ws_size,
                              hipStream_t stream)
{
  const float* x  = (const float*)d_in[0];
  const int*   er = (const int*)  d_in[1];
  const int*   ec = (const int*)  d_in[2];
  const float* ew = (const float*)d_in[3];
  const float* w1 = (const float*)d_in[4];
  const float* b1 = (const float*)d_in[5];
  const float* w2 = (const float*)d_in[6];
  const float* b2 = (const float*)d_in[7];
  const float* lw = (const float*)d_in[8];
  const float* lb = (const float*)d_in[9];
  float* out = (float*)d_out;
  int N = in_sizes[0] / 1433;
  int E = in_sizes[1];

  float* W = (float*)d_ws;
  float* hb1  = W;                              // 128
  float* hb2  = W + 128;                        // 64
  float* scal = W + 192;                        // 2
  unsigned short* w1hi = (unsigned short*)(W + 256);     // 112*KPAD = 164864 ushorts (82432 floats)
  unsigned short* w1lo = (unsigned short*)(W + 82688);   // 82432 floats
  int*   counts    = (int*)(W + 165120);        // N
  int*   row_start = counts + N;                // N
  int*   cursor    = row_start + N;             // N
  int*   blksum    = cursor + N;                // 128
  int*   ecs       = blksum + 128;              // E
  float* ews       = (float*)(ecs + E);         // E
  float* reg1 = ews + E;                        // N*100
  float* reg2 = reg1 + (size_t)N*100;           // N*100

  int nblk_scan = (N + 1023) / 1024;

  // CSR build
  hipMemsetAsync(counts, 0, (size_t)N*sizeof(int), stream);
  k_hist<<<(E + 255)/256, 256, 0, stream>>>(er, counts, E);
  k_scan1<<<nblk_scan, 256, 0, stream>>>(counts, row_start, blksum, N);
  k_scan2<<<1, 1, 0, stream>>>(blksum, nblk_scan);
  k_scan3<<<(N + 255)/256, 256, 0, stream>>>(row_start, blksum, cursor, N);
  k_scatter<<<(E + 255)/256, 256, 0, stream>>>(er, ec, ew, cursor, ecs, ews, E);

  k_prep_w1b16<<<(112*KPAD + 255)/256, 256, 0, stream>>>(w1, w1hi, w1lo);
  k_bias<<<1, 128, 0, stream>>>(b1, b2, hb1, hb2, scal);

  int nb128 = (N + 127)/128;
  k_lin1_mfma<<<nb128, 256, 0, stream>>>(x, w1hi, w1lo, hb1, scal, reg1, N);

  int nbg = (N + 3)/4;
  int nb32 = (N + 31)/32;
  k_agg_gather<100><<<nbg, 256, 0, stream>>>(reg1, row_start, counts, ecs, ews, reg2, N);
  k_layer2<<<nb32, 256, 0, stream>>>(reg2, w2, hb2, scal, reg1, N);
  k_agg_gather<64><<<nbg, 256, 0, stream>>>(reg1, row_start, counts, ecs, ews, reg2, N);
  k_decode<<<nb32, 256, 0, stream>>>(reg2, lw, lb, out, N);
}